// Round 8
// baseline (523.040 us; speedup 1.0000x reference)
//
#include <hip/hip_runtime.h>
#include <math.h>

#define DD 512
#define NH 8
#define HD 64
#define NLQ 2048
#define NLK 8192
#define LOG2E 1.4426950408889634f
#define SCQ (0.125f * LOG2E)

typedef __attribute__((ext_vector_type(8))) short bf16x8;
typedef __attribute__((ext_vector_type(8))) unsigned short u16x8;
typedef __attribute__((ext_vector_type(4))) short s16x4;
typedef __attribute__((ext_vector_type(4))) float f32x4;

#define MFMA16(a, b, c) __builtin_amdgcn_mfma_f32_16x16x32_bf16((a), (b), (c), 0, 0, 0)

__device__ __forceinline__ unsigned short f2bf(float x) {
    unsigned u = __builtin_bit_cast(unsigned, x);
    u += 0x7fffu + ((u >> 16) & 1u);
    return (unsigned short)(u >> 16);
}
__device__ __forceinline__ float bf2f(unsigned short h) {
    unsigned u = ((unsigned)h) << 16;
    return __builtin_bit_cast(float, u);
}
__device__ __forceinline__ unsigned short f2h(float x) {
    return __builtin_bit_cast(unsigned short, (_Float16)x);
}
__device__ __forceinline__ float h2f(unsigned short u) {
    return (float)__builtin_bit_cast(_Float16, u);
}
__device__ __forceinline__ int cvtpk(float a, float b) {
    int r;
    asm("v_cvt_pk_bf16_f32 %0, %1, %2" : "=v"(r) : "v"(a), "v"(b));
    return r;
}

// ---------------------------------------------------------------------------
// fp32 -> bf16 hi/lo split (weights)
// ---------------------------------------------------------------------------
__global__ __launch_bounds__(256) void cvt_hl(const float* __restrict__ x,
                                              short* __restrict__ hi,
                                              short* __restrict__ lo, int n)
{
    const int i = (blockIdx.x * 256 + threadIdx.x) * 4;
    if (i >= n) return;
    const float4 v = *(const float4*)&x[i];
    const float a[4] = {v.x, v.y, v.z, v.w};
    s16x4 h, l;
#pragma unroll
    for (int j = 0; j < 4; ++j) {
        const unsigned short hh = f2bf(a[j]);
        h[j] = (short)hh;
        l[j] = (short)f2bf(a[j] - bf2f(hh));
    }
    *(s16x4*)&hi[i] = h;
    *(s16x4*)&lo[i] = l;
}

// ---------------------------------------------------------------------------
// mask -> fp16 frag table: mh[ktile*1024 + l*16 + 4j + r]
//   = fp16(-10000*log2e * mask[ktile*64 + 16j + 4*(l>>4) + r]). 262 KB, L2-hot.
// ---------------------------------------------------------------------------
__global__ __launch_bounds__(256) void cvt_mask(const int* __restrict__ mask,
                                                unsigned short* __restrict__ mh)
{
    const int tid = blockIdx.x * 256 + threadIdx.x;   // 8192 threads
    const int ktile = tid >> 6;
    const int g = (tid >> 4) & 3;
    u16x8 o0, o1;
#pragma unroll
    for (int j = 0; j < 4; ++j)
#pragma unroll
        for (int r = 0; r < 4; ++r) {
            const int k = ktile * 64 + 16 * j + 4 * g + r;
            const float v = (-10000.f * LOG2E) * (float)mask[k];
            const int idx = 4 * j + r;
            if (idx < 8) o0[idx] = f2h(v);
            else         o1[idx - 8] = f2h(v);
        }
    *(u16x8*)&mh[(size_t)tid * 16] = o0;
    *(u16x8*)&mh[(size_t)tid * 16 + 8] = o1;
}

// ---------------------------------------------------------------------------
// FUSED QKV projection: one launch, 144 row-tiles x 4 col-tiles.
// bid<16: Q (scaled by SCQ, row out). bid<80: K (row out). else: V (transposed).
// X fp32 direct (cvt in staging, hi only), W hi/lo, 2-MFMA.
// ---------------------------------------------------------------------------
__global__ __launch_bounds__(256) void gemm_qkvf(const float* __restrict__ Q,
                                                 const float* __restrict__ K,
                                                 const float* __restrict__ V,
                                                 const short* __restrict__ Whi,
                                                 const short* __restrict__ Wlo,
                                                 const float* __restrict__ bin,
                                                 short* __restrict__ qhi,
                                                 short* __restrict__ khi,
                                                 short* __restrict__ vthi)
{
    __shared__ __align__(16) short XsH[128 * 40];
    __shared__ __align__(16) short WsH[128 * 40];
    __shared__ __align__(16) short WsL[128 * 40];

    const int bid = blockIdx.x;
    const float* X; const short *Wh, *Wl; const float* b; short* out;
    int r0; float scale; int tr;
    if (bid < 16)      { X = Q; r0 = bid * 128;        Wh = Whi;              Wl = Wlo;              b = bin;          out = qhi;  scale = SCQ; tr = 0; }
    else if (bid < 80) { X = K; r0 = (bid - 16) * 128; Wh = Whi + DD * DD;    Wl = Wlo + DD * DD;    b = bin + DD;     out = khi;  scale = 1.f; tr = 0; }
    else               { X = V; r0 = (bid - 80) * 128; Wh = Whi + 2 * DD * DD; Wl = Wlo + 2 * DD * DD; b = bin + 2 * DD; out = vthi; scale = 1.f; tr = 1; }
    const int o0 = blockIdx.y * 128;

    const int t    = threadIdx.x;
    const int wid  = t >> 6;
    const int lane = t & 63;
    const int g  = lane >> 4;
    const int c  = lane & 15;
    const int wr = wid >> 1;
    const int wc = wid & 1;
    const int srow = t >> 1;
    const int sk   = (t & 1) * 16;

    float4 xf[4];
    bf16x8 pwh[2], pwl[2];
    auto ld = [&](int kc) {
#pragma unroll
        for (int i = 0; i < 4; ++i)
            xf[i] = *(const float4*)&X[(size_t)(r0 + srow) * DD + kc + sk + 4 * i];
#pragma unroll
        for (int i = 0; i < 2; ++i) {
            pwh[i] = *(const bf16x8*)&Wh[(size_t)(o0 + srow) * DD + kc + sk + 8 * i];
            pwl[i] = *(const bf16x8*)&Wl[(size_t)(o0 + srow) * DD + kc + sk + 8 * i];
        }
    };
    auto st = [&]() {
#pragma unroll
        for (int i = 0; i < 2; ++i) {
            int4 w;
            w.x = cvtpk(xf[2 * i].x, xf[2 * i].y);
            w.y = cvtpk(xf[2 * i].z, xf[2 * i].w);
            w.z = cvtpk(xf[2 * i + 1].x, xf[2 * i + 1].y);
            w.w = cvtpk(xf[2 * i + 1].z, xf[2 * i + 1].w);
            *(int4*)&XsH[srow * 40 + sk + 8 * i] = w;
            *(bf16x8*)&WsH[srow * 40 + sk + 8 * i] = pwh[i];
            *(bf16x8*)&WsL[srow * 40 + sk + 8 * i] = pwl[i];
        }
    };

    f32x4 acc[4][4];
#pragma unroll
    for (int i = 0; i < 4; ++i)
#pragma unroll
        for (int j = 0; j < 4; ++j) acc[i][j] = (f32x4){0.f, 0.f, 0.f, 0.f};

    ld(0);
    for (int kc = 0; kc < DD; kc += 32) {
        __syncthreads();
        st();
        __syncthreads();
        if (kc + 32 < DD) ld(kc + 32);

        bf16x8 ah[4], bh[4], bl[4];
#pragma unroll
        for (int qg = 0; qg < 4; ++qg)
            ah[qg] = *(const bf16x8*)&XsH[(64 * wr + 16 * qg + c) * 40 + 8 * g];
#pragma unroll
        for (int og = 0; og < 4; ++og) {
            const int adr = (64 * wc + 16 * og + c) * 40 + 8 * g;
            bh[og] = *(const bf16x8*)&WsH[adr];
            bl[og] = *(const bf16x8*)&WsL[adr];
        }
#pragma unroll
        for (int qg = 0; qg < 4; ++qg)
#pragma unroll
            for (int og = 0; og < 4; ++og) {
                acc[qg][og] = MFMA16(ah[qg], bh[og], acc[qg][og]);
                acc[qg][og] = MFMA16(ah[qg], bl[og], acc[qg][og]);
            }
    }

#pragma unroll
    for (int qg = 0; qg < 4; ++qg)
#pragma unroll
        for (int og = 0; og < 4; ++og) {
            const int col = o0 + 64 * wc + 16 * og + c;
            const float bo = b[col];
#pragma unroll
            for (int r = 0; r < 4; ++r) {
                const int row = r0 + 64 * wr + 16 * qg + 4 * g + r;
                const float v = (acc[qg][og][r] + bo) * scale;
                if (tr) out[(size_t)col * NLK + row] = (short)f2bf(v);
                else    out[(size_t)row * DD + col]  = (short)f2bf(v);
            }
        }
}

// ---------------------------------------------------------------------------
// Out-projection: 64x64 tiles (256 blocks), X hi/lo, W hi/lo, 3-MFMA, f32 out.
// ---------------------------------------------------------------------------
__global__ __launch_bounds__(256) void gemm_out(const short* __restrict__ Xhi,
                                                const short* __restrict__ Xlo,
                                                const short* __restrict__ Whi,
                                                const short* __restrict__ Wlo,
                                                const float* __restrict__ b,
                                                float* __restrict__ Y)
{
    __shared__ __align__(16) short XsH[64 * 40];
    __shared__ __align__(16) short XsL[64 * 40];
    __shared__ __align__(16) short WsH[64 * 40];
    __shared__ __align__(16) short WsL[64 * 40];

    const int r0 = blockIdx.x * 64;
    const int o0 = blockIdx.y * 64;
    const int t    = threadIdx.x;
    const int wid  = t >> 6;
    const int lane = t & 63;
    const int g  = lane >> 4;
    const int c  = lane & 15;
    const int srow = t >> 2;
    const int sc8  = (t & 3) * 8;

    bf16x8 pxh, pxl, pwh, pwl;
    auto ld = [&](int kc) {
        pxh = *(const bf16x8*)&Xhi[(size_t)(r0 + srow) * DD + kc + sc8];
        pxl = *(const bf16x8*)&Xlo[(size_t)(r0 + srow) * DD + kc + sc8];
        pwh = *(const bf16x8*)&Whi[(size_t)(o0 + srow) * DD + kc + sc8];
        pwl = *(const bf16x8*)&Wlo[(size_t)(o0 + srow) * DD + kc + sc8];
    };
    auto st = [&]() {
        *(bf16x8*)&XsH[srow * 40 + sc8] = pxh;
        *(bf16x8*)&XsL[srow * 40 + sc8] = pxl;
        *(bf16x8*)&WsH[srow * 40 + sc8] = pwh;
        *(bf16x8*)&WsL[srow * 40 + sc8] = pwl;
    };

    f32x4 acc[4];
#pragma unroll
    for (int n = 0; n < 4; ++n) acc[n] = (f32x4){0.f, 0.f, 0.f, 0.f};

    ld(0);
    for (int kc = 0; kc < DD; kc += 32) {
        __syncthreads();
        st();
        __syncthreads();
        if (kc + 32 < DD) ld(kc + 32);

        bf16x8 ah, al, bh[4], bl[4];
        ah = *(const bf16x8*)&XsH[(wid * 16 + c) * 40 + 8 * g];
        al = *(const bf16x8*)&XsL[(wid * 16 + c) * 40 + 8 * g];
#pragma unroll
        for (int n = 0; n < 4; ++n) {
            const int adr = (16 * n + c) * 40 + 8 * g;
            bh[n] = *(const bf16x8*)&WsH[adr];
            bl[n] = *(const bf16x8*)&WsL[adr];
        }
#pragma unroll
        for (int n = 0; n < 4; ++n) {
            acc[n] = MFMA16(ah, bh[n], acc[n]);
            acc[n] = MFMA16(ah, bl[n], acc[n]);
            acc[n] = MFMA16(al, bh[n], acc[n]);
        }
    }

#pragma unroll
    for (int n = 0; n < 4; ++n) {
        const int col = o0 + 16 * n + c;
        const float bo = b[col];
#pragma unroll
        for (int r = 0; r < 4; ++r)
            Y[(size_t)(r0 + wid * 16 + 4 * g + r) * DD + col] = acc[n][r] + bo;
    }
}

// ---------------------------------------------------------------------------
// MFMA flash attention, swapped QK^T + in-register softmax.
// fp32 bias read direct (prefetched, *log2e in-kernel); fp16 mask frag table.
// setprio around MFMA clusters; defer-max rescale (THR=11.5 log2-units);
// epilogue pre-normalizes acc by 1/l (fp16-safe under defer-max).
// ---------------------------------------------------------------------------
#define QT 128
#define KT 64
#define NKC 8
#define CHUNK (NLK / NKC)
#define NT (CHUNK / KT)

__global__ __launch_bounds__(512, 8) void attn_mfma(const short* __restrict__ qhi,
                                                    const short* __restrict__ khi,
                                                    const short* __restrict__ vthi,
                                                    const float* __restrict__ bias,
                                                    const unsigned short* __restrict__ mh,
                                                    unsigned short* __restrict__ macc,
                                                    float2* __restrict__ mlb)
{
    __shared__ __align__(16) short ksh[2][KT * HD];
    __shared__ __align__(16) short vth[2][KT * HD];

    const int id = blockIdx.x;          // h*128 + qt*8 + kc
    const int h  = id >> 7;
    const int qt = (id >> 3) & 15;
    const int kc = id & 7;
    const int q0 = qt * QT;
    const int k0 = kc * CHUNK;

    const int t    = threadIdx.x;
    const int wid  = t >> 6;
    const int lane = t & 63;
    const int g  = lane >> 4;
    const int cl = lane & 15;
    const int swc = ((cl & 7) << 3);

    bf16x8 qah[2];
    {
        const size_t qr = (size_t)(q0 + wid * 16 + cl) * DD + h * HD;
        qah[0] = *(const bf16x8*)&qhi[qr + 8 * g];
        qah[1] = *(const bf16x8*)&qhi[qr + 32 + 8 * g];
    }

    const int kr0 = t >> 3;
    const int db0 = (t & 7) * 8;
    const int sw0 = ((kr0 & 7) << 3);
    bf16x8 rkh, rvh;
    auto stage_load = [&](int ktg) {
        rkh = *(const bf16x8*)&khi[(size_t)(ktg + kr0) * DD + h * HD + db0];
        rvh = *(const bf16x8*)&vthi[(size_t)(h * HD + kr0) * NLK + ktg + db0];
    };
    auto stage_write = [&](int p) {
        const int i0 = kr0 * HD + (db0 ^ sw0);
        *(bf16x8*)&ksh[p][i0] = rkh;
        *(bf16x8*)&vth[p][i0] = rvh;
    };

    // fp32 bias prefetch: lane's 16 score-values for a tile = 4 x float4
    const float* bq = bias + (size_t)(q0 + wid * 16 + cl) * NLK + 4 * g;
    float4 bpf0, bpf1, bpf2, bpf3;
    auto bias_pf = [&](int ktg) {
        bpf0 = *(const float4*)(bq + ktg);
        bpf1 = *(const float4*)(bq + ktg + 16);
        bpf2 = *(const float4*)(bq + ktg + 32);
        bpf3 = *(const float4*)(bq + ktg + 48);
    };

    f32x4 acco[4];
#pragma unroll
    for (int n = 0; n < 4; ++n) acco[n] = (f32x4){0.f, 0.f, 0.f, 0.f};
    float m_ = -1e30f, l_ = 0.f;

    const int sA = ((g & 1) << 5) + cl;
    const int sB = sA + 16;
    const bool hi2 = (g >= 2);

    stage_load(k0);
    bias_pf(k0);

    for (int it = 0; it < NT; ++it) {
        const int p = it & 1;
        stage_write(p);
        __syncthreads();
        if (it + 1 < NT) stage_load(k0 + (it + 1) * KT);

        // mask frag (L2-hot 262KB table), consumed after QK
        const size_t ma = ((size_t)(kc * NT + it) << 10) + lane * 16;
        const u16x8 mp0 = *(const u16x8*)&mh[ma];
        const u16x8 mp1 = *(const u16x8*)&mh[ma + 8];

        // ---- swapped QK^T: sc[j][r] = S[k=16j+4g+r][q=cl-row] ----
        f32x4 sc[4];
#pragma unroll
        for (int j = 0; j < 4; ++j) sc[j] = (f32x4){0.f, 0.f, 0.f, 0.f};
        __builtin_amdgcn_s_setprio(1);
#pragma unroll
        for (int j = 0; j < 4; ++j) {
            const int krow = (16 * j + cl) * HD;
#pragma unroll
            for (int s = 0; s < 2; ++s) {
                const bf16x8 kf = *(const bf16x8*)&ksh[p][krow + ((32 * s + 8 * g) ^ swc)];
                sc[j] = MFMA16(kf, qah[s], sc[j]);
            }
        }
        __builtin_amdgcn_s_setprio(0);

        // ---- bias (fp32 * log2e) + mask ----
        {
            const float4 bb[4] = {bpf0, bpf1, bpf2, bpf3};
#pragma unroll
            for (int j = 0; j < 4; ++j) {
                const float ba[4] = {bb[j].x, bb[j].y, bb[j].z, bb[j].w};
#pragma unroll
                for (int r = 0; r < 4; ++r) {
                    const int idx = 4 * j + r;
                    const float mv = h2f((idx < 8) ? (unsigned short)mp0[idx]
                                                   : (unsigned short)mp1[idx - 8]);
                    sc[j][r] = fmaf(ba[r], LOG2E, sc[j][r]) + mv;
                }
            }
        }
        if (it + 1 < NT) bias_pf(k0 + (it + 1) * KT);

        // ---- in-register softmax with defer-max ----
        float tm = fmaxf(fmaxf(fmaxf(sc[0][0], sc[0][1]), fmaxf(sc[0][2], sc[0][3])),
                         fmaxf(fmaxf(sc[1][0], sc[1][1]), fmaxf(sc[1][2], sc[1][3])));
        tm = fmaxf(tm, fmaxf(fmaxf(fmaxf(sc[2][0], sc[2][1]), fmaxf(sc[2][2], sc[2][3])),
                             fmaxf(fmaxf(sc[3][0], sc[3][1]), fmaxf(sc[3][2], sc[3][3]))));
        tm = fmaxf(tm, __shfl_xor(tm, 16));
        tm = fmaxf(tm, __shfl_xor(tm, 32));
        if (!__all(tm - m_ <= 11.5f)) {
            const float mn = fmaxf(m_, tm);
            const float al = exp2f(m_ - mn);
            float alr[4];
#pragma unroll
            for (int r = 0; r < 4; ++r) alr[r] = __shfl(al, 4 * g + r);
#pragma unroll
            for (int n = 0; n < 4; ++n)
#pragma unroll
                for (int r = 0; r < 4; ++r) acco[n][r] *= alr[r];
            l_ *= al;
            m_ = mn;
        }
        float ts = 0.f;
#pragma unroll
        for (int j = 0; j < 4; ++j)
#pragma unroll
            for (int r = 0; r < 4; ++r) {
                sc[j][r] = exp2f(sc[j][r] - m_);
                ts += sc[j][r];
            }
        ts += __shfl_xor(ts, 16);
        ts += __shfl_xor(ts, 32);
        l_ += ts;

        // ---- pack P (bf16 pairs) and redistribute to PV A-frags ----
        int Wp[4][2];
#pragma unroll
        for (int j = 0; j < 4; ++j) {
            Wp[j][0] = cvtpk(sc[j][0], sc[j][1]);
            Wp[j][1] = cvtpk(sc[j][2], sc[j][3]);
        }
        bf16x8 pah[2];
#pragma unroll
        for (int s = 0; s < 2; ++s) {
            const int a0 = __shfl(Wp[2 * s][0], sA);
            const int a1 = __shfl(Wp[2 * s][1], sA);
            const int b0 = __shfl(Wp[2 * s + 1][0], sA);
            const int b1 = __shfl(Wp[2 * s + 1][1], sA);
            const int c0 = __shfl(Wp[2 * s][0], sB);
            const int c1 = __shfl(Wp[2 * s][1], sB);
            const int d0 = __shfl(Wp[2 * s + 1][0], sB);
            const int d1 = __shfl(Wp[2 * s + 1][1], sB);
            int4 w;
            w.x = hi2 ? b0 : a0;
            w.y = hi2 ? b1 : a1;
            w.z = hi2 ? d0 : c0;
            w.w = hi2 ? d1 : c1;
            pah[s] = *(bf16x8*)&w;
        }

        // ---- PV ----
        __builtin_amdgcn_s_setprio(1);
#pragma unroll
        for (int n = 0; n < 4; ++n) {
            const int drow = (16 * n + cl) * HD;
#pragma unroll
            for (int s = 0; s < 2; ++s) {
                const bf16x8 vh = *(const bf16x8*)&vth[p][drow + ((32 * s + 8 * g) ^ swc)];
                acco[n] = MFMA16(pah[s], vh, acco[n]);
            }
        }
        __builtin_amdgcn_s_setprio(0);
    }

    // epilogue: pre-normalize by 1/l (fp16-safe), store (m,l) for combine
    const float inv = 1.f / l_;
    float linv[4];
#pragma unroll
    for (int r = 0; r < 4; ++r) linv[r] = __shfl(inv, 4 * g + r);
#pragma unroll
    for (int r = 0; r < 4; ++r) {
        const int q = q0 + wid * 16 + 4 * g + r;
        const size_t base = ((size_t)(kc * NH + h) * NLQ + q) * HD;
#pragma unroll
        for (int n = 0; n < 4; ++n)
            macc[base + 16 * n + cl] = f2h(acco[n][r] * linv[r]);
    }
    if (g == 0)
        mlb[(size_t)(kc * NH + h) * NLQ + q0 + wid * 16 + cl] = make_float2(m_, l_);
}

// ---------------------------------------------------------------------------
// Combine: partials are pre-normalized; weight = exp2(m_c - M) * l_c.
// ---------------------------------------------------------------------------
__global__ __launch_bounds__(256) void attn_combine(const unsigned short* __restrict__ macc,
                                                    const float2* __restrict__ mlb,
                                                    short* __restrict__ aohi,
                                                    short* __restrict__ aolo)
{
    const int row = blockIdx.x * 4 + (threadIdx.x >> 6);  // h*NLQ + q
    const int d   = threadIdx.x & 63;
    float m[NKC], l[NKC];
#pragma unroll
    for (int c = 0; c < NKC; ++c) {
        const float2 v = mlb[(size_t)c * NH * NLQ + row];
        m[c] = v.x; l[c] = v.y;
    }
    float M = m[0];
#pragma unroll
    for (int c = 1; c < NKC; ++c) M = fmaxf(M, m[c]);
    float w[NKC], L = 0.f;
#pragma unroll
    for (int c = 0; c < NKC; ++c) { w[c] = exp2f(m[c] - M) * l[c]; L += w[c]; }
    float s = 0.f;
#pragma unroll
    for (int c = 0; c < NKC; ++c)
        s += h2f(macc[((size_t)c * NH * NLQ + row) * HD + d]) * w[c];
    const float v = s / L;
    const int hh = row >> 11;
    const int q  = row & (NLQ - 1);
    const size_t o = (size_t)q * DD + hh * HD + d;
    const unsigned short hb = f2bf(v);
    aohi[o] = (short)hb;
    aolo[o] = (short)f2bf(v - bf2f(hb));
}

extern "C" void kernel_launch(void* const* d_in, const int* in_sizes, int n_in,
                              void* d_out, int out_size, void* d_ws, size_t ws_size,
                              hipStream_t stream)
{
    (void)in_sizes; (void)n_in; (void)out_size; (void)ws_size;
    const float* Q    = (const float*)d_in[0];
    const float* K    = (const float*)d_in[1];
    const float* V    = (const float*)d_in[2];
    const int*   mask = (const int*)d_in[3];
    const float* bias = (const float*)d_in[4];
    const float* Win  = (const float*)d_in[5];
    const float* bin  = (const float*)d_in[6];
    const float* Wout = (const float*)d_in[7];
    const float* bout = (const float*)d_in[8];
    float* out = (float*)d_out;

    // ---- workspace (~44 MB flat) ----
    short* qhi_  = (short*)d_ws;                                // 2 MB
    short* khi_  = qhi_  + (size_t)NLQ * DD;                    // 8 MB
    short* vthi_ = khi_  + (size_t)NLK * DD;                    // 8 MB
    short* whi_  = vthi_ + (size_t)NLK * DD;                    // 2 MB
    short* wlo_  = whi_  + (size_t)4 * DD * DD;                 // 2 MB
    unsigned short* mh_   = (unsigned short*)(wlo_ + (size_t)4 * DD * DD);  // 256 KB
    unsigned short* macc_ = mh_ + (size_t)128 * 64 * 16;        // 16.8 MB
    float2* ml_  = (float2*)(macc_ + (size_t)NKC * NH * NLQ * HD);  // 1 MB
    short* aohi_ = (short*)(ml_ + (size_t)NKC * NH * NLQ);      // 2 MB
    short* aolo_ = aohi_ + (size_t)NLQ * DD;                    // 2 MB

    const int CV = 256 * 4;

    // weights -> bf16 hi/lo ; mask -> fp16 frag table
    cvt_hl<<<(3 * DD * DD + CV - 1) / CV, 256, 0, stream>>>(Win,  whi_, wlo_, 3 * DD * DD);
    cvt_hl<<<(DD * DD + CV - 1) / CV, 256, 0, stream>>>(Wout, whi_ + 3 * DD * DD, wlo_ + 3 * DD * DD, DD * DD);
    cvt_mask<<<32, 256, 0, stream>>>(mask, mh_);

    // fused QKV projection (576 blocks)
    gemm_qkvf<<<dim3(144, 4), 256, 0, stream>>>(Q, K, V, whi_, wlo_, bin, qhi_, khi_, vthi_);

    // attention (k-split NKC=8) + combine
    attn_mfma<<<dim3(NH * 16 * NKC), 512, 0, stream>>>(qhi_, khi_, vthi_, bias, mh_, macc_, ml_);
    attn_combine<<<dim3(NH * NLQ / 4), 256, 0, stream>>>(macc_, ml_, aohi_, aolo_);

    // out projection (64x64 tiles, exact split path)
    gemm_out<<<dim3(NLQ / 64, DD / 64), 256, 0, stream>>>(aohi_, aolo_, whi_ + 3 * DD * DD, wlo_ + 3 * DD * DD,
                                                          bout, out);
}

// Round 9
// 299.685 us; speedup vs baseline: 1.7453x; 1.7453x over previous
//
#include <hip/hip_runtime.h>
#include <math.h>

#define DD 512
#define NH 8
#define HD 64
#define NLQ 2048
#define NLK 8192
#define LOG2E 1.4426950408889634f
#define SCQ (0.125f * LOG2E)

typedef __attribute__((ext_vector_type(8))) short bf16x8;
typedef __attribute__((ext_vector_type(8))) unsigned short u16x8;
typedef __attribute__((ext_vector_type(4))) short s16x4;
typedef __attribute__((ext_vector_type(4))) float f32x4;

#define MFMA16(a, b, c) __builtin_amdgcn_mfma_f32_16x16x32_bf16((a), (b), (c), 0, 0, 0)

__device__ __forceinline__ unsigned short f2bf(float x) {
    unsigned u = __builtin_bit_cast(unsigned, x);
    u += 0x7fffu + ((u >> 16) & 1u);
    return (unsigned short)(u >> 16);
}
__device__ __forceinline__ float bf2f(unsigned short h) {
    unsigned u = ((unsigned)h) << 16;
    return __builtin_bit_cast(float, u);
}
__device__ __forceinline__ unsigned short f2h(float x) {
    return __builtin_bit_cast(unsigned short, (_Float16)x);
}
__device__ __forceinline__ float h2f(unsigned short u) {
    return (float)__builtin_bit_cast(_Float16, u);
}
__device__ __forceinline__ int cvtpk(float a, float b) {
    int r;
    asm("v_cvt_pk_bf16_f32 %0, %1, %2" : "=v"(r) : "v"(a), "v"(b));
    return r;
}

// ---------------------------------------------------------------------------
// fp32 -> bf16 hi/lo split (weights)
// ---------------------------------------------------------------------------
__global__ __launch_bounds__(256) void cvt_hl(const float* __restrict__ x,
                                              short* __restrict__ hi,
                                              short* __restrict__ lo, int n)
{
    const int i = (blockIdx.x * 256 + threadIdx.x) * 4;
    if (i >= n) return;
    const float4 v = *(const float4*)&x[i];
    const float a[4] = {v.x, v.y, v.z, v.w};
    s16x4 h, l;
#pragma unroll
    for (int j = 0; j < 4; ++j) {
        const unsigned short hh = f2bf(a[j]);
        h[j] = (short)hh;
        l[j] = (short)f2bf(a[j] - bf2f(hh));
    }
    *(s16x4*)&hi[i] = h;
    *(s16x4*)&lo[i] = l;
}

// ---------------------------------------------------------------------------
// bias+mask -> fp16 in log2 units, fragment-packed for swapped-QK order:
// addr = ((Qg*128 + kt)<<10) + lane*16 + j*4 + r
// value = (bias[q][k] - 1e4*mask[k]) * log2e,
//   q = Qg*16 + (lane&15), k = kt*64 + 16j + 4*(lane>>4) + r.
// Coalesced consumer reads + 8x cross-head L2 reuse (R8 lesson: direct fp32
// fragment-order reads overfetch 894 MB and are BW-fatal).
// ---------------------------------------------------------------------------
__global__ __launch_bounds__(256) void cvt_bias(const float* __restrict__ bias,
                                                const int* __restrict__ mask,
                                                unsigned short* __restrict__ bh)
{
    const int tid  = blockIdx.x * 256 + threadIdx.x;
    const int tile = tid >> 6;          // (Qg*128 + kt)
    const int l    = tid & 63;
    const int q    = (tile >> 7) * 16 + (l & 15);
    const int kb   = (tile & 127) * 64 + 4 * (l >> 4);
    u16x8 o0, o1;
#pragma unroll
    for (int j = 0; j < 4; ++j) {
        const float4 bv = *(const float4*)&bias[(size_t)q * NLK + kb + 16 * j];
        const int4   mv = *(const int4*)&mask[kb + 16 * j];
        const float a[4] = {bv.x, bv.y, bv.z, bv.w};
        const int   m[4] = {mv.x, mv.y, mv.z, mv.w};
#pragma unroll
        for (int r = 0; r < 4; ++r) {
            const float v = (a[r] - 10000.f * (float)m[r]) * LOG2E;
            const int idx = j * 4 + r;
            if (idx < 8) o0[idx] = f2h(v);
            else         o1[idx - 8] = f2h(v);
        }
    }
    const size_t base = ((size_t)tid) * 16;
    *(u16x8*)&bh[base] = o0;
    *(u16x8*)&bh[base + 8] = o1;
}

// ---------------------------------------------------------------------------
// FUSED QKV projection: one launch, 144 row-tiles x 4 col-tiles.
// bid<16: Q (scaled SCQ). bid<80: K. else: V (transposed out).
// X fp32 direct (cvt in staging, hi only), W hi/lo, 2-MFMA.
// ---------------------------------------------------------------------------
__global__ __launch_bounds__(256) void gemm_qkvf(const float* __restrict__ Q,
                                                 const float* __restrict__ K,
                                                 const float* __restrict__ V,
                                                 const short* __restrict__ Whi,
                                                 const short* __restrict__ Wlo,
                                                 const float* __restrict__ bin,
                                                 short* __restrict__ qhi,
                                                 short* __restrict__ khi,
                                                 short* __restrict__ vthi)
{
    __shared__ __align__(16) short XsH[128 * 40];
    __shared__ __align__(16) short WsH[128 * 40];
    __shared__ __align__(16) short WsL[128 * 40];

    const int bid = blockIdx.x;
    const float* X; const short *Wh, *Wl; const float* b; short* out;
    int r0; float scale; int tr;
    if (bid < 16)      { X = Q; r0 = bid * 128;        Wh = Whi;               Wl = Wlo;               b = bin;          out = qhi;  scale = SCQ; tr = 0; }
    else if (bid < 80) { X = K; r0 = (bid - 16) * 128; Wh = Whi + DD * DD;     Wl = Wlo + DD * DD;     b = bin + DD;     out = khi;  scale = 1.f; tr = 0; }
    else               { X = V; r0 = (bid - 80) * 128; Wh = Whi + 2 * DD * DD; Wl = Wlo + 2 * DD * DD; b = bin + 2 * DD; out = vthi; scale = 1.f; tr = 1; }
    const int o0 = blockIdx.y * 128;

    const int t    = threadIdx.x;
    const int wid  = t >> 6;
    const int lane = t & 63;
    const int g  = lane >> 4;
    const int c  = lane & 15;
    const int wr = wid >> 1;
    const int wc = wid & 1;
    const int srow = t >> 1;
    const int sk   = (t & 1) * 16;

    float4 xf[4];
    bf16x8 pwh[2], pwl[2];
    auto ld = [&](int kc) {
#pragma unroll
        for (int i = 0; i < 4; ++i)
            xf[i] = *(const float4*)&X[(size_t)(r0 + srow) * DD + kc + sk + 4 * i];
#pragma unroll
        for (int i = 0; i < 2; ++i) {
            pwh[i] = *(const bf16x8*)&Wh[(size_t)(o0 + srow) * DD + kc + sk + 8 * i];
            pwl[i] = *(const bf16x8*)&Wl[(size_t)(o0 + srow) * DD + kc + sk + 8 * i];
        }
    };
    auto st = [&]() {
#pragma unroll
        for (int i = 0; i < 2; ++i) {
            int4 w;
            w.x = cvtpk(xf[2 * i].x, xf[2 * i].y);
            w.y = cvtpk(xf[2 * i].z, xf[2 * i].w);
            w.z = cvtpk(xf[2 * i + 1].x, xf[2 * i + 1].y);
            w.w = cvtpk(xf[2 * i + 1].z, xf[2 * i + 1].w);
            *(int4*)&XsH[srow * 40 + sk + 8 * i] = w;
            *(bf16x8*)&WsH[srow * 40 + sk + 8 * i] = pwh[i];
            *(bf16x8*)&WsL[srow * 40 + sk + 8 * i] = pwl[i];
        }
    };

    f32x4 acc[4][4];
#pragma unroll
    for (int i = 0; i < 4; ++i)
#pragma unroll
        for (int j = 0; j < 4; ++j) acc[i][j] = (f32x4){0.f, 0.f, 0.f, 0.f};

    ld(0);
    for (int kc = 0; kc < DD; kc += 32) {
        __syncthreads();
        st();
        __syncthreads();
        if (kc + 32 < DD) ld(kc + 32);

        bf16x8 ah[4], bh[4], bl[4];
#pragma unroll
        for (int qg = 0; qg < 4; ++qg)
            ah[qg] = *(const bf16x8*)&XsH[(64 * wr + 16 * qg + c) * 40 + 8 * g];
#pragma unroll
        for (int og = 0; og < 4; ++og) {
            const int adr = (64 * wc + 16 * og + c) * 40 + 8 * g;
            bh[og] = *(const bf16x8*)&WsH[adr];
            bl[og] = *(const bf16x8*)&WsL[adr];
        }
#pragma unroll
        for (int qg = 0; qg < 4; ++qg)
#pragma unroll
            for (int og = 0; og < 4; ++og) {
                acc[qg][og] = MFMA16(ah[qg], bh[og], acc[qg][og]);
                acc[qg][og] = MFMA16(ah[qg], bl[og], acc[qg][og]);
            }
    }

#pragma unroll
    for (int qg = 0; qg < 4; ++qg)
#pragma unroll
        for (int og = 0; og < 4; ++og) {
            const int col = o0 + 64 * wc + 16 * og + c;
            const float bo = b[col];
#pragma unroll
            for (int r = 0; r < 4; ++r) {
                const int row = r0 + 64 * wr + 16 * qg + 4 * g + r;
                const float v = (acc[qg][og][r] + bo) * scale;
                if (tr) out[(size_t)col * NLK + row] = (short)f2bf(v);
                else    out[(size_t)row * DD + col]  = (short)f2bf(v);
            }
        }
}

// ---------------------------------------------------------------------------
// Out-projection: 64x64 tiles (256 blocks), X hi/lo, W hi/lo, 3-MFMA, f32 out.
// ---------------------------------------------------------------------------
__global__ __launch_bounds__(256) void gemm_out(const short* __restrict__ Xhi,
                                                const short* __restrict__ Xlo,
                                                const short* __restrict__ Whi,
                                                const short* __restrict__ Wlo,
                                                const float* __restrict__ b,
                                                float* __restrict__ Y)
{
    __shared__ __align__(16) short XsH[64 * 40];
    __shared__ __align__(16) short XsL[64 * 40];
    __shared__ __align__(16) short WsH[64 * 40];
    __shared__ __align__(16) short WsL[64 * 40];

    const int r0 = blockIdx.x * 64;
    const int o0 = blockIdx.y * 64;
    const int t    = threadIdx.x;
    const int wid  = t >> 6;
    const int lane = t & 63;
    const int g  = lane >> 4;
    const int c  = lane & 15;
    const int srow = t >> 2;
    const int sc8  = (t & 3) * 8;

    bf16x8 pxh, pxl, pwh, pwl;
    auto ld = [&](int kc) {
        pxh = *(const bf16x8*)&Xhi[(size_t)(r0 + srow) * DD + kc + sc8];
        pxl = *(const bf16x8*)&Xlo[(size_t)(r0 + srow) * DD + kc + sc8];
        pwh = *(const bf16x8*)&Whi[(size_t)(o0 + srow) * DD + kc + sc8];
        pwl = *(const bf16x8*)&Wlo[(size_t)(o0 + srow) * DD + kc + sc8];
    };
    auto st = [&]() {
        *(bf16x8*)&XsH[srow * 40 + sc8] = pxh;
        *(bf16x8*)&XsL[srow * 40 + sc8] = pxl;
        *(bf16x8*)&WsH[srow * 40 + sc8] = pwh;
        *(bf16x8*)&WsL[srow * 40 + sc8] = pwl;
    };

    f32x4 acc[4];
#pragma unroll
    for (int n = 0; n < 4; ++n) acc[n] = (f32x4){0.f, 0.f, 0.f, 0.f};

    ld(0);
    for (int kc = 0; kc < DD; kc += 32) {
        __syncthreads();
        st();
        __syncthreads();
        if (kc + 32 < DD) ld(kc + 32);

        bf16x8 ah, al, bh[4], bl[4];
        ah = *(const bf16x8*)&XsH[(wid * 16 + c) * 40 + 8 * g];
        al = *(const bf16x8*)&XsL[(wid * 16 + c) * 40 + 8 * g];
#pragma unroll
        for (int n = 0; n < 4; ++n) {
            const int adr = (16 * n + c) * 40 + 8 * g;
            bh[n] = *(const bf16x8*)&WsH[adr];
            bl[n] = *(const bf16x8*)&WsL[adr];
        }
#pragma unroll
        for (int n = 0; n < 4; ++n) {
            acc[n] = MFMA16(ah, bh[n], acc[n]);
            acc[n] = MFMA16(ah, bl[n], acc[n]);
            acc[n] = MFMA16(al, bh[n], acc[n]);
        }
    }

#pragma unroll
    for (int n = 0; n < 4; ++n) {
        const int col = o0 + 16 * n + c;
        const float bo = b[col];
#pragma unroll
        for (int r = 0; r < 4; ++r)
            Y[(size_t)(r0 + wid * 16 + 4 * g + r) * DD + col] = acc[n][r] + bo;
    }
}

// ---------------------------------------------------------------------------
// MFMA flash attention: swapped QK^T + in-register softmax + packed fp16 bias.
// setprio around MFMA clusters; defer-max (THR=11.5 log2-units); epilogue
// pre-normalizes acc by 1/l. launch_bounds(512,8) (R8: 78% occupancy).
// ---------------------------------------------------------------------------
#define QT 128
#define KT 64
#define NKC 8
#define CHUNK (NLK / NKC)
#define NT (CHUNK / KT)

__global__ __launch_bounds__(512, 8) void attn_mfma(const short* __restrict__ qhi,
                                                    const short* __restrict__ khi,
                                                    const short* __restrict__ vthi,
                                                    const unsigned short* __restrict__ biash,
                                                    unsigned short* __restrict__ macc,
                                                    float2* __restrict__ mlb)
{
    __shared__ __align__(16) short ksh[2][KT * HD];
    __shared__ __align__(16) short vth[2][KT * HD];

    const int id = blockIdx.x;          // h*128 + qt*8 + kc
    const int h  = id >> 7;
    const int qt = (id >> 3) & 15;
    const int kc = id & 7;
    const int q0 = qt * QT;
    const int k0 = kc * CHUNK;

    const int t    = threadIdx.x;
    const int wid  = t >> 6;
    const int lane = t & 63;
    const int g  = lane >> 4;
    const int cl = lane & 15;
    const int swc = ((cl & 7) << 3);

    bf16x8 qah[2];
    {
        const size_t qr = (size_t)(q0 + wid * 16 + cl) * DD + h * HD;
        qah[0] = *(const bf16x8*)&qhi[qr + 8 * g];
        qah[1] = *(const bf16x8*)&qhi[qr + 32 + 8 * g];
    }

    const int kr0 = t >> 3;
    const int db0 = (t & 7) * 8;
    const int sw0 = ((kr0 & 7) << 3);
    bf16x8 rkh, rvh;
    auto stage_load = [&](int ktg) {
        rkh = *(const bf16x8*)&khi[(size_t)(ktg + kr0) * DD + h * HD + db0];
        rvh = *(const bf16x8*)&vthi[(size_t)(h * HD + kr0) * NLK + ktg + db0];
    };
    auto stage_write = [&](int p) {
        const int i0 = kr0 * HD + (db0 ^ sw0);
        *(bf16x8*)&ksh[p][i0] = rkh;
        *(bf16x8*)&vth[p][i0] = rvh;
    };

    // packed fp16 bias prefetch: lane's 16 frag values = 2 x 16B coalesced
    const size_t btile0 = (size_t)(qt * 8 + wid) * 128;
    const int boff = lane * 16;
    u16x8 bp0, bp1;
    auto bias_pf = [&](int ktile) {
        const size_t ba = ((btile0 + (size_t)ktile) << 10) + boff;
        bp0 = *(const u16x8*)&biash[ba];
        bp1 = *(const u16x8*)&biash[ba + 8];
    };

    f32x4 acco[4];
#pragma unroll
    for (int n = 0; n < 4; ++n) acco[n] = (f32x4){0.f, 0.f, 0.f, 0.f};
    float m_ = -1e30f, l_ = 0.f;

    const int sA = ((g & 1) << 5) + cl;
    const int sB = sA + 16;
    const bool hi2 = (g >= 2);

    stage_load(k0);
    bias_pf(kc * NT);

    for (int it = 0; it < NT; ++it) {
        const int p = it & 1;
        stage_write(p);
        __syncthreads();
        if (it + 1 < NT) stage_load(k0 + (it + 1) * KT);

        // ---- swapped QK^T: sc[j][r] = S[k=16j+4g+r][q=cl-row] (log2 units) ----
        f32x4 sc[4];
#pragma unroll
        for (int j = 0; j < 4; ++j) sc[j] = (f32x4){0.f, 0.f, 0.f, 0.f};
        __builtin_amdgcn_s_setprio(1);
#pragma unroll
        for (int j = 0; j < 4; ++j) {
            const int krow = (16 * j + cl) * HD;
#pragma unroll
            for (int s = 0; s < 2; ++s) {
                const bf16x8 kf = *(const bf16x8*)&ksh[p][krow + ((32 * s + 8 * g) ^ swc)];
                sc[j] = MFMA16(kf, qah[s], sc[j]);
            }
        }
        __builtin_amdgcn_s_setprio(0);

        // ---- add packed bias (mask + log2e prefolded) ----
#pragma unroll
        for (int j = 0; j < 4; ++j)
#pragma unroll
            for (int r = 0; r < 4; ++r) {
                const int i = j * 4 + r;
                const unsigned short u =
                    (i < 8) ? (unsigned short)bp0[i] : (unsigned short)bp1[i - 8];
                sc[j][r] += h2f(u);
            }
        if (it + 1 < NT) bias_pf(kc * NT + it + 1);

        // ---- in-register softmax with defer-max ----
        float tm = fmaxf(fmaxf(fmaxf(sc[0][0], sc[0][1]), fmaxf(sc[0][2], sc[0][3])),
                         fmaxf(fmaxf(sc[1][0], sc[1][1]), fmaxf(sc[1][2], sc[1][3])));
        tm = fmaxf(tm, fmaxf(fmaxf(fmaxf(sc[2][0], sc[2][1]), fmaxf(sc[2][2], sc[2][3])),
                             fmaxf(fmaxf(sc[3][0], sc[3][1]), fmaxf(sc[3][2], sc[3][3]))));
        tm = fmaxf(tm, __shfl_xor(tm, 16));
        tm = fmaxf(tm, __shfl_xor(tm, 32));
        if (!__all(tm - m_ <= 11.5f)) {
            const float mn = fmaxf(m_, tm);
            const float al = exp2f(m_ - mn);
            float alr[4];
#pragma unroll
            for (int r = 0; r < 4; ++r) alr[r] = __shfl(al, 4 * g + r);
#pragma unroll
            for (int n = 0; n < 4; ++n)
#pragma unroll
                for (int r = 0; r < 4; ++r) acco[n][r] *= alr[r];
            l_ *= al;
            m_ = mn;
        }
        float ts = 0.f;
#pragma unroll
        for (int j = 0; j < 4; ++j)
#pragma unroll
            for (int r = 0; r < 4; ++r) {
                sc[j][r] = exp2f(sc[j][r] - m_);
                ts += sc[j][r];
            }
        ts += __shfl_xor(ts, 16);
        ts += __shfl_xor(ts, 32);
        l_ += ts;

        // ---- pack P (bf16 pairs) and redistribute to PV A-frags ----
        int Wp[4][2];
#pragma unroll
        for (int j = 0; j < 4; ++j) {
            Wp[j][0] = cvtpk(sc[j][0], sc[j][1]);
            Wp[j][1] = cvtpk(sc[j][2], sc[j][3]);
        }
        bf16x8 pah[2];
#pragma unroll
        for (int s = 0; s < 2; ++s) {
            const int a0 = __shfl(Wp[2 * s][0], sA);
            const int a1 = __shfl(Wp[2 * s][1], sA);
            const int b0 = __shfl(Wp[2 * s + 1][0], sA);
            const int b1 = __shfl(Wp[2 * s + 1][1], sA);
            const int c0 = __shfl(Wp[2 * s][0], sB);
            const int c1 = __shfl(Wp[2 * s][1], sB);
            const int d0 = __shfl(Wp[2 * s + 1][0], sB);
            const int d1 = __shfl(Wp[2 * s + 1][1], sB);
            int4 w;
            w.x = hi2 ? b0 : a0;
            w.y = hi2 ? b1 : a1;
            w.z = hi2 ? d0 : c0;
            w.w = hi2 ? d1 : c1;
            pah[s] = *(bf16x8*)&w;
        }

        // ---- PV ----
        __builtin_amdgcn_s_setprio(1);
#pragma unroll
        for (int n = 0; n < 4; ++n) {
            const int drow = (16 * n + cl) * HD;
#pragma unroll
            for (int s = 0; s < 2; ++s) {
                const bf16x8 vh = *(const bf16x8*)&vth[p][drow + ((32 * s + 8 * g) ^ swc)];
                acco[n] = MFMA16(pah[s], vh, acco[n]);
            }
        }
        __builtin_amdgcn_s_setprio(0);
    }

    // epilogue: pre-normalize by 1/l (fp16-safe), store (m,l) for combine
    const float inv = 1.f / l_;
    float linv[4];
#pragma unroll
    for (int r = 0; r < 4; ++r) linv[r] = __shfl(inv, 4 * g + r);
#pragma unroll
    for (int r = 0; r < 4; ++r) {
        const int q = q0 + wid * 16 + 4 * g + r;
        const size_t base = ((size_t)(kc * NH + h) * NLQ + q) * HD;
#pragma unroll
        for (int n = 0; n < 4; ++n)
            macc[base + 16 * n + cl] = f2h(acco[n][r] * linv[r]);
    }
    if (g == 0)
        mlb[(size_t)(kc * NH + h) * NLQ + q0 + wid * 16 + cl] = make_float2(m_, l_);
}

// ---------------------------------------------------------------------------
// Combine: partials pre-normalized; weight = exp2(m_c - M) * l_c.
// ---------------------------------------------------------------------------
__global__ __launch_bounds__(256) void attn_combine(const unsigned short* __restrict__ macc,
                                                    const float2* __restrict__ mlb,
                                                    short* __restrict__ aohi,
                                                    short* __restrict__ aolo)
{
    const int row = blockIdx.x * 4 + (threadIdx.x >> 6);  // h*NLQ + q
    const int d   = threadIdx.x & 63;
    float m[NKC], l[NKC];
#pragma unroll
    for (int c = 0; c < NKC; ++c) {
        const float2 v = mlb[(size_t)c * NH * NLQ + row];
        m[c] = v.x; l[c] = v.y;
    }
    float M = m[0];
#pragma unroll
    for (int c = 1; c < NKC; ++c) M = fmaxf(M, m[c]);
    float w[NKC], L = 0.f;
#pragma unroll
    for (int c = 0; c < NKC; ++c) { w[c] = exp2f(m[c] - M) * l[c]; L += w[c]; }
    float s = 0.f;
#pragma unroll
    for (int c = 0; c < NKC; ++c)
        s += h2f(macc[((size_t)c * NH * NLQ + row) * HD + d]) * w[c];
    const float v = s / L;
    const int hh = row >> 11;
    const int q  = row & (NLQ - 1);
    const size_t o = (size_t)q * DD + hh * HD + d;
    const unsigned short hb = f2bf(v);
    aohi[o] = (short)hb;
    aolo[o] = (short)f2bf(v - bf2f(hb));
}

extern "C" void kernel_launch(void* const* d_in, const int* in_sizes, int n_in,
                              void* d_out, int out_size, void* d_ws, size_t ws_size,
                              hipStream_t stream)
{
    (void)in_sizes; (void)n_in; (void)out_size; (void)ws_size;
    const float* Q    = (const float*)d_in[0];
    const float* K    = (const float*)d_in[1];
    const float* V    = (const float*)d_in[2];
    const int*   mask = (const int*)d_in[3];
    const float* bias = (const float*)d_in[4];
    const float* Win  = (const float*)d_in[5];
    const float* bin  = (const float*)d_in[6];
    const float* Wout = (const float*)d_in[7];
    const float* bout = (const float*)d_in[8];
    float* out = (float*)d_out;

    // ---- workspace (~76 MB flat) ----
    short* qhi_  = (short*)d_ws;                                // 2 MB
    short* khi_  = qhi_  + (size_t)NLQ * DD;                    // 8 MB
    short* vthi_ = khi_  + (size_t)NLK * DD;                    // 8 MB
    short* whi_  = vthi_ + (size_t)NLK * DD;                    // 2 MB
    short* wlo_  = whi_  + (size_t)4 * DD * DD;                 // 2 MB
    unsigned short* biash_ = (unsigned short*)(wlo_ + (size_t)4 * DD * DD); // 32 MB
    unsigned short* macc_  = biash_ + (size_t)NLQ * NLK;        // 16.8 MB
    float2* ml_  = (float2*)(macc_ + (size_t)NKC * NH * NLQ * HD);  // 1 MB
    short* aohi_ = (short*)(ml_ + (size_t)NKC * NH * NLQ);      // 2 MB
    short* aolo_ = aohi_ + (size_t)NLQ * DD;                    // 2 MB

    const int CV = 256 * 4;

    // weights -> bf16 hi/lo ; bias+mask -> fp16 fragment pack (log2 units)
    cvt_hl<<<(3 * DD * DD + CV - 1) / CV, 256, 0, stream>>>(Win,  whi_, wlo_, 3 * DD * DD);
    cvt_hl<<<(DD * DD + CV - 1) / CV, 256, 0, stream>>>(Wout, whi_ + 3 * DD * DD, wlo_ + 3 * DD * DD, DD * DD);
    cvt_bias<<<(int)(((size_t)NLQ * NLK / 16) / 256), 256, 0, stream>>>(bias, mask, biash_);

    // fused QKV projection (576 blocks)
    gemm_qkvf<<<dim3(144, 4), 256, 0, stream>>>(Q, K, V, whi_, wlo_, bin, qhi_, khi_, vthi_);

    // attention (k-split NKC=8) + combine
    attn_mfma<<<dim3(NH * 16 * NKC), 512, 0, stream>>>(qhi_, khi_, vthi_, biash_, macc_, ml_);
    attn_combine<<<dim3(NH * NLQ / 4), 256, 0, stream>>>(macc_, ml_, aohi_, aolo_);

    // out projection (64x64 tiles, exact split path)
    gemm_out<<<dim3(NLQ / 64, DD / 64), 256, 0, stream>>>(aohi_, aolo_, whi_ + 3 * DD * DD, wlo_ + 3 * DD * DD,
                                                          bout, out);
}

// Round 10
// 167.581 us; speedup vs baseline: 3.1211x; 1.7883x over previous
//
#include <hip/hip_runtime.h>
#include <math.h>

#define DD 512
#define NH 8
#define HD 64
#define NLQ 2048
#define NLK 8192
#define LOG2E 1.4426950408889634f
#define SCQ (0.125f * LOG2E)

typedef __attribute__((ext_vector_type(8))) short bf16x8;
typedef __attribute__((ext_vector_type(8))) unsigned short u16x8;
typedef __attribute__((ext_vector_type(4))) short s16x4;
typedef __attribute__((ext_vector_type(4))) float f32x4;

#define MFMA16(a, b, c) __builtin_amdgcn_mfma_f32_16x16x32_bf16((a), (b), (c), 0, 0, 0)

__device__ __forceinline__ unsigned short f2bf(float x) {
    unsigned u = __builtin_bit_cast(unsigned, x);
    u += 0x7fffu + ((u >> 16) & 1u);
    return (unsigned short)(u >> 16);
}
__device__ __forceinline__ float bf2f(unsigned short h) {
    unsigned u = ((unsigned)h) << 16;
    return __builtin_bit_cast(float, u);
}
__device__ __forceinline__ unsigned short f2h(float x) {
    return __builtin_bit_cast(unsigned short, (_Float16)x);
}
__device__ __forceinline__ float h2f(unsigned short u) {
    return (float)__builtin_bit_cast(_Float16, u);
}
__device__ __forceinline__ int cvtpk(float a, float b) {
    int r;
    asm("v_cvt_pk_bf16_f32 %0, %1, %2" : "=v"(r) : "v"(a), "v"(b));
    return r;
}

// ---------------------------------------------------------------------------
// fp32 -> bf16 hi/lo split (weights)
// ---------------------------------------------------------------------------
__global__ __launch_bounds__(256) void cvt_hl(const float* __restrict__ x,
                                              short* __restrict__ hi,
                                              short* __restrict__ lo, int n)
{
    const int i = (blockIdx.x * 256 + threadIdx.x) * 4;
    if (i >= n) return;
    const float4 v = *(const float4*)&x[i];
    const float a[4] = {v.x, v.y, v.z, v.w};
    s16x4 h, l;
#pragma unroll
    for (int j = 0; j < 4; ++j) {
        const unsigned short hh = f2bf(a[j]);
        h[j] = (short)hh;
        l[j] = (short)f2bf(a[j] - bf2f(hh));
    }
    *(s16x4*)&hi[i] = h;
    *(s16x4*)&lo[i] = l;
}

// ---------------------------------------------------------------------------
// bias+mask -> fp16 in log2 units, fragment-packed for swapped-QK order:
// addr = ((Qg*128 + kt)<<10) + lane*16 + j*4 + r
// value = (bias[q][k] - 1e4*mask[k]) * log2e,
//   q = Qg*16 + (lane&15), k = kt*64 + 16j + 4*(lane>>4) + r.
// Coalesced consumer reads + 8x cross-head L2 reuse (R8 lesson: direct fp32
// fragment-order reads overfetch 894 MB and are BW-fatal).
// ---------------------------------------------------------------------------
__global__ __launch_bounds__(256) void cvt_bias(const float* __restrict__ bias,
                                                const int* __restrict__ mask,
                                                unsigned short* __restrict__ bh)
{
    const int tid  = blockIdx.x * 256 + threadIdx.x;
    const int tile = tid >> 6;          // (Qg*128 + kt)
    const int l    = tid & 63;
    const int q    = (tile >> 7) * 16 + (l & 15);
    const int kb   = (tile & 127) * 64 + 4 * (l >> 4);
    u16x8 o0, o1;
#pragma unroll
    for (int j = 0; j < 4; ++j) {
        const float4 bv = *(const float4*)&bias[(size_t)q * NLK + kb + 16 * j];
        const int4   mv = *(const int4*)&mask[kb + 16 * j];
        const float a[4] = {bv.x, bv.y, bv.z, bv.w};
        const int   m[4] = {mv.x, mv.y, mv.z, mv.w};
#pragma unroll
        for (int r = 0; r < 4; ++r) {
            const float v = (a[r] - 10000.f * (float)m[r]) * LOG2E;
            const int idx = j * 4 + r;
            if (idx < 8) o0[idx] = f2h(v);
            else         o1[idx - 8] = f2h(v);
        }
    }
    const size_t base = ((size_t)tid) * 16;
    *(u16x8*)&bh[base] = o0;
    *(u16x8*)&bh[base + 8] = o1;
}

// ---------------------------------------------------------------------------
// FUSED QKV projection: one launch, 144 row-tiles x 4 col-tiles.
// bid<16: Q (scaled SCQ). bid<80: K. else: V (transposed out).
// X fp32 direct (cvt in staging, hi only), W hi/lo, 2-MFMA.
// ---------------------------------------------------------------------------
__global__ __launch_bounds__(256) void gemm_qkvf(const float* __restrict__ Q,
                                                 const float* __restrict__ K,
                                                 const float* __restrict__ V,
                                                 const short* __restrict__ Whi,
                                                 const short* __restrict__ Wlo,
                                                 const float* __restrict__ bin,
                                                 short* __restrict__ qhi,
                                                 short* __restrict__ khi,
                                                 short* __restrict__ vthi)
{
    __shared__ __align__(16) short XsH[128 * 40];
    __shared__ __align__(16) short WsH[128 * 40];
    __shared__ __align__(16) short WsL[128 * 40];

    const int bid = blockIdx.x;
    const float* X; const short *Wh, *Wl; const float* b; short* out;
    int r0; float scale; int tr;
    if (bid < 16)      { X = Q; r0 = bid * 128;        Wh = Whi;               Wl = Wlo;               b = bin;          out = qhi;  scale = SCQ; tr = 0; }
    else if (bid < 80) { X = K; r0 = (bid - 16) * 128; Wh = Whi + DD * DD;     Wl = Wlo + DD * DD;     b = bin + DD;     out = khi;  scale = 1.f; tr = 0; }
    else               { X = V; r0 = (bid - 80) * 128; Wh = Whi + 2 * DD * DD; Wl = Wlo + 2 * DD * DD; b = bin + 2 * DD; out = vthi; scale = 1.f; tr = 1; }
    const int o0 = blockIdx.y * 128;

    const int t    = threadIdx.x;
    const int wid  = t >> 6;
    const int lane = t & 63;
    const int g  = lane >> 4;
    const int c  = lane & 15;
    const int wr = wid >> 1;
    const int wc = wid & 1;
    const int srow = t >> 1;
    const int sk   = (t & 1) * 16;

    float4 xf[4];
    bf16x8 pwh[2], pwl[2];
    auto ld = [&](int kc) {
#pragma unroll
        for (int i = 0; i < 4; ++i)
            xf[i] = *(const float4*)&X[(size_t)(r0 + srow) * DD + kc + sk + 4 * i];
#pragma unroll
        for (int i = 0; i < 2; ++i) {
            pwh[i] = *(const bf16x8*)&Wh[(size_t)(o0 + srow) * DD + kc + sk + 8 * i];
            pwl[i] = *(const bf16x8*)&Wl[(size_t)(o0 + srow) * DD + kc + sk + 8 * i];
        }
    };
    auto st = [&]() {
#pragma unroll
        for (int i = 0; i < 2; ++i) {
            int4 w;
            w.x = cvtpk(xf[2 * i].x, xf[2 * i].y);
            w.y = cvtpk(xf[2 * i].z, xf[2 * i].w);
            w.z = cvtpk(xf[2 * i + 1].x, xf[2 * i + 1].y);
            w.w = cvtpk(xf[2 * i + 1].z, xf[2 * i + 1].w);
            *(int4*)&XsH[srow * 40 + sk + 8 * i] = w;
            *(bf16x8*)&WsH[srow * 40 + sk + 8 * i] = pwh[i];
            *(bf16x8*)&WsL[srow * 40 + sk + 8 * i] = pwl[i];
        }
    };

    f32x4 acc[4][4];
#pragma unroll
    for (int i = 0; i < 4; ++i)
#pragma unroll
        for (int j = 0; j < 4; ++j) acc[i][j] = (f32x4){0.f, 0.f, 0.f, 0.f};

    ld(0);
    for (int kc = 0; kc < DD; kc += 32) {
        __syncthreads();
        st();
        __syncthreads();
        if (kc + 32 < DD) ld(kc + 32);

        bf16x8 ah[4], bh[4], bl[4];
#pragma unroll
        for (int qg = 0; qg < 4; ++qg)
            ah[qg] = *(const bf16x8*)&XsH[(64 * wr + 16 * qg + c) * 40 + 8 * g];
#pragma unroll
        for (int og = 0; og < 4; ++og) {
            const int adr = (64 * wc + 16 * og + c) * 40 + 8 * g;
            bh[og] = *(const bf16x8*)&WsH[adr];
            bl[og] = *(const bf16x8*)&WsL[adr];
        }
#pragma unroll
        for (int qg = 0; qg < 4; ++qg)
#pragma unroll
            for (int og = 0; og < 4; ++og) {
                acc[qg][og] = MFMA16(ah[qg], bh[og], acc[qg][og]);
                acc[qg][og] = MFMA16(ah[qg], bl[og], acc[qg][og]);
            }
    }

#pragma unroll
    for (int qg = 0; qg < 4; ++qg)
#pragma unroll
        for (int og = 0; og < 4; ++og) {
            const int col = o0 + 64 * wc + 16 * og + c;
            const float bo = b[col];
#pragma unroll
            for (int r = 0; r < 4; ++r) {
                const int row = r0 + 64 * wr + 16 * qg + 4 * g + r;
                const float v = (acc[qg][og][r] + bo) * scale;
                if (tr) out[(size_t)col * NLK + row] = (short)f2bf(v);
                else    out[(size_t)row * DD + col]  = (short)f2bf(v);
            }
        }
}

// ---------------------------------------------------------------------------
// Out-projection: 64x64 tiles (256 blocks), X hi/lo, W hi/lo, 3-MFMA, f32 out.
// ---------------------------------------------------------------------------
__global__ __launch_bounds__(256) void gemm_out(const short* __restrict__ Xhi,
                                                const short* __restrict__ Xlo,
                                                const short* __restrict__ Whi,
                                                const short* __restrict__ Wlo,
                                                const float* __restrict__ b,
                                                float* __restrict__ Y)
{
    __shared__ __align__(16) short XsH[64 * 40];
    __shared__ __align__(16) short XsL[64 * 40];
    __shared__ __align__(16) short WsH[64 * 40];
    __shared__ __align__(16) short WsL[64 * 40];

    const int r0 = blockIdx.x * 64;
    const int o0 = blockIdx.y * 64;
    const int t    = threadIdx.x;
    const int wid  = t >> 6;
    const int lane = t & 63;
    const int g  = lane >> 4;
    const int c  = lane & 15;
    const int srow = t >> 2;
    const int sc8  = (t & 3) * 8;

    bf16x8 pxh, pxl, pwh, pwl;
    auto ld = [&](int kc) {
        pxh = *(const bf16x8*)&Xhi[(size_t)(r0 + srow) * DD + kc + sc8];
        pxl = *(const bf16x8*)&Xlo[(size_t)(r0 + srow) * DD + kc + sc8];
        pwh = *(const bf16x8*)&Whi[(size_t)(o0 + srow) * DD + kc + sc8];
        pwl = *(const bf16x8*)&Wlo[(size_t)(o0 + srow) * DD + kc + sc8];
    };
    auto st = [&]() {
        *(bf16x8*)&XsH[srow * 40 + sc8] = pxh;
        *(bf16x8*)&XsL[srow * 40 + sc8] = pxl;
        *(bf16x8*)&WsH[srow * 40 + sc8] = pwh;
        *(bf16x8*)&WsL[srow * 40 + sc8] = pwl;
    };

    f32x4 acc[4];
#pragma unroll
    for (int n = 0; n < 4; ++n) acc[n] = (f32x4){0.f, 0.f, 0.f, 0.f};

    ld(0);
    for (int kc = 0; kc < DD; kc += 32) {
        __syncthreads();
        st();
        __syncthreads();
        if (kc + 32 < DD) ld(kc + 32);

        bf16x8 ah, al, bh[4], bl[4];
        ah = *(const bf16x8*)&XsH[(wid * 16 + c) * 40 + 8 * g];
        al = *(const bf16x8*)&XsL[(wid * 16 + c) * 40 + 8 * g];
#pragma unroll
        for (int n = 0; n < 4; ++n) {
            const int adr = (16 * n + c) * 40 + 8 * g;
            bh[n] = *(const bf16x8*)&WsH[adr];
            bl[n] = *(const bf16x8*)&WsL[adr];
        }
#pragma unroll
        for (int n = 0; n < 4; ++n) {
            acc[n] = MFMA16(ah, bh[n], acc[n]);
            acc[n] = MFMA16(ah, bl[n], acc[n]);
            acc[n] = MFMA16(al, bh[n], acc[n]);
        }
    }

#pragma unroll
    for (int n = 0; n < 4; ++n) {
        const int col = o0 + 16 * n + c;
        const float bo = b[col];
#pragma unroll
        for (int r = 0; r < 4; ++r)
            Y[(size_t)(r0 + wid * 16 + 4 * g + r) * DD + col] = acc[n][r] + bo;
    }
}

// ---------------------------------------------------------------------------
// MFMA flash attention: swapped QK^T + in-register softmax + packed fp16 bias.
// launch_bounds(512,4): VGPR cap 128 -- R9's (512,8) forced VGPR=32 and the
// kernel SPILLED (WRITE_SIZE 425 MB of scratch, attn 215us). R7-proven config.
// setprio around MFMA clusters; defer-max (THR=11.5 log2-units); epilogue
// pre-normalizes acc by 1/l (fp16-safe).
// ---------------------------------------------------------------------------
#define QT 128
#define KT 64
#define NKC 8
#define CHUNK (NLK / NKC)
#define NT (CHUNK / KT)

__global__ __launch_bounds__(512, 4) void attn_mfma(const short* __restrict__ qhi,
                                                    const short* __restrict__ khi,
                                                    const short* __restrict__ vthi,
                                                    const unsigned short* __restrict__ biash,
                                                    unsigned short* __restrict__ macc,
                                                    float2* __restrict__ mlb)
{
    __shared__ __align__(16) short ksh[2][KT * HD];
    __shared__ __align__(16) short vth[2][KT * HD];

    const int id = blockIdx.x;          // h*128 + qt*8 + kc
    const int h  = id >> 7;
    const int qt = (id >> 3) & 15;
    const int kc = id & 7;
    const int q0 = qt * QT;
    const int k0 = kc * CHUNK;

    const int t    = threadIdx.x;
    const int wid  = t >> 6;
    const int lane = t & 63;
    const int g  = lane >> 4;
    const int cl = lane & 15;
    const int swc = ((cl & 7) << 3);

    bf16x8 qah[2];
    {
        const size_t qr = (size_t)(q0 + wid * 16 + cl) * DD + h * HD;
        qah[0] = *(const bf16x8*)&qhi[qr + 8 * g];
        qah[1] = *(const bf16x8*)&qhi[qr + 32 + 8 * g];
    }

    const int kr0 = t >> 3;
    const int db0 = (t & 7) * 8;
    const int sw0 = ((kr0 & 7) << 3);
    bf16x8 rkh, rvh;
    auto stage_load = [&](int ktg) {
        rkh = *(const bf16x8*)&khi[(size_t)(ktg + kr0) * DD + h * HD + db0];
        rvh = *(const bf16x8*)&vthi[(size_t)(h * HD + kr0) * NLK + ktg + db0];
    };
    auto stage_write = [&](int p) {
        const int i0 = kr0 * HD + (db0 ^ sw0);
        *(bf16x8*)&ksh[p][i0] = rkh;
        *(bf16x8*)&vth[p][i0] = rvh;
    };

    // packed fp16 bias prefetch: lane's 16 frag values = 2 x 16B coalesced
    const size_t btile0 = (size_t)(qt * 8 + wid) * 128;
    const int boff = lane * 16;
    u16x8 bp0, bp1;
    auto bias_pf = [&](int ktile) {
        const size_t ba = ((btile0 + (size_t)ktile) << 10) + boff;
        bp0 = *(const u16x8*)&biash[ba];
        bp1 = *(const u16x8*)&biash[ba + 8];
    };

    f32x4 acco[4];
#pragma unroll
    for (int n = 0; n < 4; ++n) acco[n] = (f32x4){0.f, 0.f, 0.f, 0.f};
    float m_ = -1e30f, l_ = 0.f;

    const int sA = ((g & 1) << 5) + cl;
    const int sB = sA + 16;
    const bool hi2 = (g >= 2);

    stage_load(k0);
    bias_pf(kc * NT);

    for (int it = 0; it < NT; ++it) {
        const int p = it & 1;
        stage_write(p);
        __syncthreads();
        if (it + 1 < NT) stage_load(k0 + (it + 1) * KT);

        // ---- swapped QK^T: sc[j][r] = S[k=16j+4g+r][q=cl-row] (log2 units) ----
        f32x4 sc[4];
#pragma unroll
        for (int j = 0; j < 4; ++j) sc[j] = (f32x4){0.f, 0.f, 0.f, 0.f};
        __builtin_amdgcn_s_setprio(1);
#pragma unroll
        for (int j = 0; j < 4; ++j) {
            const int krow = (16 * j + cl) * HD;
#pragma unroll
            for (int s = 0; s < 2; ++s) {
                const bf16x8 kf = *(const bf16x8*)&ksh[p][krow + ((32 * s + 8 * g) ^ swc)];
                sc[j] = MFMA16(kf, qah[s], sc[j]);
            }
        }
        __builtin_amdgcn_s_setprio(0);

        // ---- add packed bias (mask + log2e prefolded) ----
#pragma unroll
        for (int j = 0; j < 4; ++j)
#pragma unroll
            for (int r = 0; r < 4; ++r) {
                const int i = j * 4 + r;
                const unsigned short u =
                    (i < 8) ? (unsigned short)bp0[i] : (unsigned short)bp1[i - 8];
                sc[j][r] += h2f(u);
            }
        if (it + 1 < NT) bias_pf(kc * NT + it + 1);

        // ---- in-register softmax with defer-max ----
        float tm = fmaxf(fmaxf(fmaxf(sc[0][0], sc[0][1]), fmaxf(sc[0][2], sc[0][3])),
                         fmaxf(fmaxf(sc[1][0], sc[1][1]), fmaxf(sc[1][2], sc[1][3])));
        tm = fmaxf(tm, fmaxf(fmaxf(fmaxf(sc[2][0], sc[2][1]), fmaxf(sc[2][2], sc[2][3])),
                             fmaxf(fmaxf(sc[3][0], sc[3][1]), fmaxf(sc[3][2], sc[3][3]))));
        tm = fmaxf(tm, __shfl_xor(tm, 16));
        tm = fmaxf(tm, __shfl_xor(tm, 32));
        if (!__all(tm - m_ <= 11.5f)) {
            const float mn = fmaxf(m_, tm);
            const float al = exp2f(m_ - mn);
            float alr[4];
#pragma unroll
            for (int r = 0; r < 4; ++r) alr[r] = __shfl(al, 4 * g + r);
#pragma unroll
            for (int n = 0; n < 4; ++n)
#pragma unroll
                for (int r = 0; r < 4; ++r) acco[n][r] *= alr[r];
            l_ *= al;
            m_ = mn;
        }
        float ts = 0.f;
#pragma unroll
        for (int j = 0; j < 4; ++j)
#pragma unroll
            for (int r = 0; r < 4; ++r) {
                sc[j][r] = exp2f(sc[j][r] - m_);
                ts += sc[j][r];
            }
        ts += __shfl_xor(ts, 16);
        ts += __shfl_xor(ts, 32);
        l_ += ts;

        // ---- pack P (bf16 pairs) and redistribute to PV A-frags ----
        int Wp[4][2];
#pragma unroll
        for (int j = 0; j < 4; ++j) {
            Wp[j][0] = cvtpk(sc[j][0], sc[j][1]);
            Wp[j][1] = cvtpk(sc[j][2], sc[j][3]);
        }
        bf16x8 pah[2];
#pragma unroll
        for (int s = 0; s < 2; ++s) {
            const int a0 = __shfl(Wp[2 * s][0], sA);
            const int a1 = __shfl(Wp[2 * s][1], sA);
            const int b0 = __shfl(Wp[2 * s + 1][0], sA);
            const int b1 = __shfl(Wp[2 * s + 1][1], sA);
            const int c0 = __shfl(Wp[2 * s][0], sB);
            const int c1 = __shfl(Wp[2 * s][1], sB);
            const int d0 = __shfl(Wp[2 * s + 1][0], sB);
            const int d1 = __shfl(Wp[2 * s + 1][1], sB);
            int4 w;
            w.x = hi2 ? b0 : a0;
            w.y = hi2 ? b1 : a1;
            w.z = hi2 ? d0 : c0;
            w.w = hi2 ? d1 : c1;
            pah[s] = *(bf16x8*)&w;
        }

        // ---- PV ----
        __builtin_amdgcn_s_setprio(1);
#pragma unroll
        for (int n = 0; n < 4; ++n) {
            const int drow = (16 * n + cl) * HD;
#pragma unroll
            for (int s = 0; s < 2; ++s) {
                const bf16x8 vh = *(const bf16x8*)&vth[p][drow + ((32 * s + 8 * g) ^ swc)];
                acco[n] = MFMA16(pah[s], vh, acco[n]);
            }
        }
        __builtin_amdgcn_s_setprio(0);
    }

    // epilogue: pre-normalize by 1/l (fp16-safe), store (m,l) for combine
    const float inv = 1.f / l_;
    float linv[4];
#pragma unroll
    for (int r = 0; r < 4; ++r) linv[r] = __shfl(inv, 4 * g + r);
#pragma unroll
    for (int r = 0; r < 4; ++r) {
        const int q = q0 + wid * 16 + 4 * g + r;
        const size_t base = ((size_t)(kc * NH + h) * NLQ + q) * HD;
#pragma unroll
        for (int n = 0; n < 4; ++n)
            macc[base + 16 * n + cl] = f2h(acco[n][r] * linv[r]);
    }
    if (g == 0)
        mlb[(size_t)(kc * NH + h) * NLQ + q0 + wid * 16 + cl] = make_float2(m_, l_);
}

// ---------------------------------------------------------------------------
// Combine: partials pre-normalized; weight = exp2(m_c - M) * l_c.
// ---------------------------------------------------------------------------
__global__ __launch_bounds__(256) void attn_combine(const unsigned short* __restrict__ macc,
                                                    const float2* __restrict__ mlb,
                                                    short* __restrict__ aohi,
                                                    short* __restrict__ aolo)
{
    const int row = blockIdx.x * 4 + (threadIdx.x >> 6);  // h*NLQ + q
    const int d   = threadIdx.x & 63;
    float m[NKC], l[NKC];
#pragma unroll
    for (int c = 0; c < NKC; ++c) {
        const float2 v = mlb[(size_t)c * NH * NLQ + row];
        m[c] = v.x; l[c] = v.y;
    }
    float M = m[0];
#pragma unroll
    for (int c = 1; c < NKC; ++c) M = fmaxf(M, m[c]);
    float w[NKC], L = 0.f;
#pragma unroll
    for (int c = 0; c < NKC; ++c) { w[c] = exp2f(m[c] - M) * l[c]; L += w[c]; }
    float s = 0.f;
#pragma unroll
    for (int c = 0; c < NKC; ++c)
        s += h2f(macc[((size_t)c * NH * NLQ + row) * HD + d]) * w[c];
    const float v = s / L;
    const int hh = row >> 11;
    const int q  = row & (NLQ - 1);
    const size_t o = (size_t)q * DD + hh * HD + d;
    const unsigned short hb = f2bf(v);
    aohi[o] = (short)hb;
    aolo[o] = (short)f2bf(v - bf2f(hb));
}

extern "C" void kernel_launch(void* const* d_in, const int* in_sizes, int n_in,
                              void* d_out, int out_size, void* d_ws, size_t ws_size,
                              hipStream_t stream)
{
    (void)in_sizes; (void)n_in; (void)out_size; (void)ws_size;
    const float* Q    = (const float*)d_in[0];
    const float* K    = (const float*)d_in[1];
    const float* V    = (const float*)d_in[2];
    const int*   mask = (const int*)d_in[3];
    const float* bias = (const float*)d_in[4];
    const float* Win  = (const float*)d_in[5];
    const float* bin  = (const float*)d_in[6];
    const float* Wout = (const float*)d_in[7];
    const float* bout = (const float*)d_in[8];
    float* out = (float*)d_out;

    // ---- workspace (~76 MB flat) ----
    short* qhi_  = (short*)d_ws;                                // 2 MB
    short* khi_  = qhi_  + (size_t)NLQ * DD;                    // 8 MB
    short* vthi_ = khi_  + (size_t)NLK * DD;                    // 8 MB
    short* whi_  = vthi_ + (size_t)NLK * DD;                    // 2 MB
    short* wlo_  = whi_  + (size_t)4 * DD * DD;                 // 2 MB
    unsigned short* biash_ = (unsigned short*)(wlo_ + (size_t)4 * DD * DD); // 32 MB
    unsigned short* macc_  = biash_ + (size_t)NLQ * NLK;        // 16.8 MB
    float2* ml_  = (float2*)(macc_ + (size_t)NKC * NH * NLQ * HD);  // 1 MB
    short* aohi_ = (short*)(ml_ + (size_t)NKC * NH * NLQ);      // 2 MB
    short* aolo_ = aohi_ + (size_t)NLQ * DD;                    // 2 MB

    const int CV = 256 * 4;

    // weights -> bf16 hi/lo ; bias+mask -> fp16 fragment pack (log2 units)
    cvt_hl<<<(3 * DD * DD + CV - 1) / CV, 256, 0, stream>>>(Win,  whi_, wlo_, 3 * DD * DD);
    cvt_hl<<<(DD * DD + CV - 1) / CV, 256, 0, stream>>>(Wout, whi_ + 3 * DD * DD, wlo_ + 3 * DD * DD, DD * DD);
    cvt_bias<<<(int)(((size_t)NLQ * NLK / 16) / 256), 256, 0, stream>>>(bias, mask, biash_);

    // fused QKV projection (576 blocks)
    gemm_qkvf<<<dim3(144, 4), 256, 0, stream>>>(Q, K, V, whi_, wlo_, bin, qhi_, khi_, vthi_);

    // attention (k-split NKC=8) + combine
    attn_mfma<<<dim3(NH * 16 * NKC), 512, 0, stream>>>(qhi_, khi_, vthi_, biash_, macc_, ml_);
    attn_combine<<<dim3(NH * NLQ / 4), 256, 0, stream>>>(macc_, ml_, aohi_, aolo_);

    // out projection (64x64 tiles, exact split path)
    gemm_out<<<dim3(NLQ / 64, DD / 64), 256, 0, stream>>>(aohi_, aolo_, whi_ + 3 * DD * DD, wlo_ + 3 * DD * DD,
                                                          bout, out);
}

// Round 11
// 165.733 us; speedup vs baseline: 3.1559x; 1.0112x over previous
//
#include <hip/hip_runtime.h>
#include <math.h>

#define DD 512
#define NH 8
#define HD 64
#define NLQ 2048
#define NLK 8192
#define LOG2E 1.4426950408889634f
#define SCQ (0.125f * LOG2E)

typedef __attribute__((ext_vector_type(8))) short bf16x8;
typedef __attribute__((ext_vector_type(8))) unsigned short u16x8;
typedef __attribute__((ext_vector_type(4))) short s16x4;
typedef __attribute__((ext_vector_type(4))) float f32x4;

#define MFMA16(a, b, c) __builtin_amdgcn_mfma_f32_16x16x32_bf16((a), (b), (c), 0, 0, 0)

__device__ __forceinline__ unsigned short f2bf(float x) {
    unsigned u = __builtin_bit_cast(unsigned, x);
    u += 0x7fffu + ((u >> 16) & 1u);
    return (unsigned short)(u >> 16);
}
__device__ __forceinline__ float bf2f(unsigned short h) {
    unsigned u = ((unsigned)h) << 16;
    return __builtin_bit_cast(float, u);
}
__device__ __forceinline__ unsigned short f2h(float x) {
    return __builtin_bit_cast(unsigned short, (_Float16)x);
}
__device__ __forceinline__ float h2f(unsigned short u) {
    return (float)__builtin_bit_cast(_Float16, u);
}
__device__ __forceinline__ int cvtpk(float a, float b) {
    int r;
    asm("v_cvt_pk_bf16_f32 %0, %1, %2" : "=v"(r) : "v"(a), "v"(b));
    return r;
}

// ---------------------------------------------------------------------------
// fp32 -> bf16 hi/lo split (weights)
// ---------------------------------------------------------------------------
__global__ __launch_bounds__(256) void cvt_hl(const float* __restrict__ x,
                                              short* __restrict__ hi,
                                              short* __restrict__ lo, int n)
{
    const int i = (blockIdx.x * 256 + threadIdx.x) * 4;
    if (i >= n) return;
    const float4 v = *(const float4*)&x[i];
    const float a[4] = {v.x, v.y, v.z, v.w};
    s16x4 h, l;
#pragma unroll
    for (int j = 0; j < 4; ++j) {
        const unsigned short hh = f2bf(a[j]);
        h[j] = (short)hh;
        l[j] = (short)f2bf(a[j] - bf2f(hh));
    }
    *(s16x4*)&hi[i] = h;
    *(s16x4*)&lo[i] = l;
}

// ---------------------------------------------------------------------------
// bias+mask -> fp16 in log2 units, fragment-packed for swapped-QK order:
// addr = ((Qg*128 + kt)<<10) + lane*16 + j*4 + r
// value = (bias[q][k] - 1e4*mask[k]) * log2e,
//   q = Qg*16 + (lane&15), k = kt*64 + 16j + 4*(lane>>4) + r.
// ---------------------------------------------------------------------------
__global__ __launch_bounds__(256) void cvt_bias(const float* __restrict__ bias,
                                                const int* __restrict__ mask,
                                                unsigned short* __restrict__ bh)
{
    const int tid  = blockIdx.x * 256 + threadIdx.x;
    const int tile = tid >> 6;          // (Qg*128 + kt)
    const int l    = tid & 63;
    const int q    = (tile >> 7) * 16 + (l & 15);
    const int kb   = (tile & 127) * 64 + 4 * (l >> 4);
    u16x8 o0, o1;
#pragma unroll
    for (int j = 0; j < 4; ++j) {
        const float4 bv = *(const float4*)&bias[(size_t)q * NLK + kb + 16 * j];
        const int4   mv = *(const int4*)&mask[kb + 16 * j];
        const float a[4] = {bv.x, bv.y, bv.z, bv.w};
        const int   m[4] = {mv.x, mv.y, mv.z, mv.w};
#pragma unroll
        for (int r = 0; r < 4; ++r) {
            const float v = (a[r] - 10000.f * (float)m[r]) * LOG2E;
            const int idx = j * 4 + r;
            if (idx < 8) o0[idx] = f2h(v);
            else         o1[idx - 8] = f2h(v);
        }
    }
    const size_t base = ((size_t)tid) * 16;
    *(u16x8*)&bh[base] = o0;
    *(u16x8*)&bh[base + 8] = o1;
}

// ---------------------------------------------------------------------------
// FUSED QKV projection: one launch, 144 row-tiles x 4 col-tiles.
// ---------------------------------------------------------------------------
__global__ __launch_bounds__(256) void gemm_qkvf(const float* __restrict__ Q,
                                                 const float* __restrict__ K,
                                                 const float* __restrict__ V,
                                                 const short* __restrict__ Whi,
                                                 const short* __restrict__ Wlo,
                                                 const float* __restrict__ bin,
                                                 short* __restrict__ qhi,
                                                 short* __restrict__ khi,
                                                 short* __restrict__ vthi)
{
    __shared__ __align__(16) short XsH[128 * 40];
    __shared__ __align__(16) short WsH[128 * 40];
    __shared__ __align__(16) short WsL[128 * 40];

    const int bid = blockIdx.x;
    const float* X; const short *Wh, *Wl; const float* b; short* out;
    int r0; float scale; int tr;
    if (bid < 16)      { X = Q; r0 = bid * 128;        Wh = Whi;               Wl = Wlo;               b = bin;          out = qhi;  scale = SCQ; tr = 0; }
    else if (bid < 80) { X = K; r0 = (bid - 16) * 128; Wh = Whi + DD * DD;     Wl = Wlo + DD * DD;     b = bin + DD;     out = khi;  scale = 1.f; tr = 0; }
    else               { X = V; r0 = (bid - 80) * 128; Wh = Whi + 2 * DD * DD; Wl = Wlo + 2 * DD * DD; b = bin + 2 * DD; out = vthi; scale = 1.f; tr = 1; }
    const int o0 = blockIdx.y * 128;

    const int t    = threadIdx.x;
    const int wid  = t >> 6;
    const int lane = t & 63;
    const int g  = lane >> 4;
    const int c  = lane & 15;
    const int wr = wid >> 1;
    const int wc = wid & 1;
    const int srow = t >> 1;
    const int sk   = (t & 1) * 16;

    float4 xf[4];
    bf16x8 pwh[2], pwl[2];
    auto ld = [&](int kc) {
#pragma unroll
        for (int i = 0; i < 4; ++i)
            xf[i] = *(const float4*)&X[(size_t)(r0 + srow) * DD + kc + sk + 4 * i];
#pragma unroll
        for (int i = 0; i < 2; ++i) {
            pwh[i] = *(const bf16x8*)&Wh[(size_t)(o0 + srow) * DD + kc + sk + 8 * i];
            pwl[i] = *(const bf16x8*)&Wl[(size_t)(o0 + srow) * DD + kc + sk + 8 * i];
        }
    };
    auto st = [&]() {
#pragma unroll
        for (int i = 0; i < 2; ++i) {
            int4 w;
            w.x = cvtpk(xf[2 * i].x, xf[2 * i].y);
            w.y = cvtpk(xf[2 * i].z, xf[2 * i].w);
            w.z = cvtpk(xf[2 * i + 1].x, xf[2 * i + 1].y);
            w.w = cvtpk(xf[2 * i + 1].z, xf[2 * i + 1].w);
            *(int4*)&XsH[srow * 40 + sk + 8 * i] = w;
            *(bf16x8*)&WsH[srow * 40 + sk + 8 * i] = pwh[i];
            *(bf16x8*)&WsL[srow * 40 + sk + 8 * i] = pwl[i];
        }
    };

    f32x4 acc[4][4];
#pragma unroll
    for (int i = 0; i < 4; ++i)
#pragma unroll
        for (int j = 0; j < 4; ++j) acc[i][j] = (f32x4){0.f, 0.f, 0.f, 0.f};

    ld(0);
    for (int kc = 0; kc < DD; kc += 32) {
        __syncthreads();
        st();
        __syncthreads();
        if (kc + 32 < DD) ld(kc + 32);

        bf16x8 ah[4], bh[4], bl[4];
#pragma unroll
        for (int qg = 0; qg < 4; ++qg)
            ah[qg] = *(const bf16x8*)&XsH[(64 * wr + 16 * qg + c) * 40 + 8 * g];
#pragma unroll
        for (int og = 0; og < 4; ++og) {
            const int adr = (64 * wc + 16 * og + c) * 40 + 8 * g;
            bh[og] = *(const bf16x8*)&WsH[adr];
            bl[og] = *(const bf16x8*)&WsL[adr];
        }
#pragma unroll
        for (int qg = 0; qg < 4; ++qg)
#pragma unroll
            for (int og = 0; og < 4; ++og) {
                acc[qg][og] = MFMA16(ah[qg], bh[og], acc[qg][og]);
                acc[qg][og] = MFMA16(ah[qg], bl[og], acc[qg][og]);
            }
    }

#pragma unroll
    for (int qg = 0; qg < 4; ++qg)
#pragma unroll
        for (int og = 0; og < 4; ++og) {
            const int col = o0 + 64 * wc + 16 * og + c;
            const float bo = b[col];
#pragma unroll
            for (int r = 0; r < 4; ++r) {
                const int row = r0 + 64 * wr + 16 * qg + 4 * g + r;
                const float v = (acc[qg][og][r] + bo) * scale;
                if (tr) out[(size_t)col * NLK + row] = (short)f2bf(v);
                else    out[(size_t)row * DD + col]  = (short)f2bf(v);
            }
        }
}

// ---------------------------------------------------------------------------
// Out-projection: 64x64 tiles (256 blocks), X hi/lo, W hi/lo, 3-MFMA, f32 out.
// ---------------------------------------------------------------------------
__global__ __launch_bounds__(256) void gemm_out(const short* __restrict__ Xhi,
                                                const short* __restrict__ Xlo,
                                                const short* __restrict__ Whi,
                                                const short* __restrict__ Wlo,
                                                const float* __restrict__ b,
                                                float* __restrict__ Y)
{
    __shared__ __align__(16) short XsH[64 * 40];
    __shared__ __align__(16) short XsL[64 * 40];
    __shared__ __align__(16) short WsH[64 * 40];
    __shared__ __align__(16) short WsL[64 * 40];

    const int r0 = blockIdx.x * 64;
    const int o0 = blockIdx.y * 64;
    const int t    = threadIdx.x;
    const int wid  = t >> 6;
    const int lane = t & 63;
    const int g  = lane >> 4;
    const int c  = lane & 15;
    const int srow = t >> 2;
    const int sc8  = (t & 3) * 8;

    bf16x8 pxh, pxl, pwh, pwl;
    auto ld = [&](int kc) {
        pxh = *(const bf16x8*)&Xhi[(size_t)(r0 + srow) * DD + kc + sc8];
        pxl = *(const bf16x8*)&Xlo[(size_t)(r0 + srow) * DD + kc + sc8];
        pwh = *(const bf16x8*)&Whi[(size_t)(o0 + srow) * DD + kc + sc8];
        pwl = *(const bf16x8*)&Wlo[(size_t)(o0 + srow) * DD + kc + sc8];
    };
    auto st = [&]() {
        *(bf16x8*)&XsH[srow * 40 + sc8] = pxh;
        *(bf16x8*)&XsL[srow * 40 + sc8] = pxl;
        *(bf16x8*)&WsH[srow * 40 + sc8] = pwh;
        *(bf16x8*)&WsL[srow * 40 + sc8] = pwl;
    };

    f32x4 acc[4];
#pragma unroll
    for (int n = 0; n < 4; ++n) acc[n] = (f32x4){0.f, 0.f, 0.f, 0.f};

    ld(0);
    for (int kc = 0; kc < DD; kc += 32) {
        __syncthreads();
        st();
        __syncthreads();
        if (kc + 32 < DD) ld(kc + 32);

        bf16x8 ah, al, bh[4], bl[4];
        ah = *(const bf16x8*)&XsH[(wid * 16 + c) * 40 + 8 * g];
        al = *(const bf16x8*)&XsL[(wid * 16 + c) * 40 + 8 * g];
#pragma unroll
        for (int n = 0; n < 4; ++n) {
            const int adr = (16 * n + c) * 40 + 8 * g;
            bh[n] = *(const bf16x8*)&WsH[adr];
            bl[n] = *(const bf16x8*)&WsL[adr];
        }
#pragma unroll
        for (int n = 0; n < 4; ++n) {
            acc[n] = MFMA16(ah, bh[n], acc[n]);
            acc[n] = MFMA16(ah, bl[n], acc[n]);
            acc[n] = MFMA16(al, bh[n], acc[n]);
        }
    }

#pragma unroll
    for (int n = 0; n < 4; ++n) {
        const int col = o0 + 16 * n + c;
        const float bo = b[col];
#pragma unroll
        for (int r = 0; r < 4; ++r)
            Y[(size_t)(r0 + wid * 16 + 4 * g + r) * DD + col] = acc[n][r] + bo;
    }
}

// ---------------------------------------------------------------------------
// MFMA flash attention: swapped QK^T + in-register softmax.
// R11: (a) bias enters as the QK MFMA's C-in (deletes 16 adds/tile);
// (b) softmax denominator l computed on the matrix pipe via P x ones MFMA
//     (deletes 15 adds + 2 shfl/tile; numerator and denominator now use the
//     SAME bf16-rounded P). launch_bounds(512,4): VGPR cap 128 -- (512,8)
//     forced VGPR=32 and spilled (R9: 425 MB scratch writes).
// ---------------------------------------------------------------------------
#define QT 128
#define KT 64
#define NKC 8
#define CHUNK (NLK / NKC)
#define NT (CHUNK / KT)

__global__ __launch_bounds__(512, 4) void attn_mfma(const short* __restrict__ qhi,
                                                    const short* __restrict__ khi,
                                                    const short* __restrict__ vthi,
                                                    const unsigned short* __restrict__ biash,
                                                    unsigned short* __restrict__ macc,
                                                    float2* __restrict__ mlb)
{
    __shared__ __align__(16) short ksh[2][KT * HD];
    __shared__ __align__(16) short vth[2][KT * HD];

    const int id = blockIdx.x;          // h*128 + qt*8 + kc
    const int h  = id >> 7;
    const int qt = (id >> 3) & 15;
    const int kc = id & 7;
    const int q0 = qt * QT;
    const int k0 = kc * CHUNK;

    const int t    = threadIdx.x;
    const int wid  = t >> 6;
    const int lane = t & 63;
    const int g  = lane >> 4;
    const int cl = lane & 15;
    const int swc = ((cl & 7) << 3);

    bf16x8 qah[2];
    {
        const size_t qr = (size_t)(q0 + wid * 16 + cl) * DD + h * HD;
        qah[0] = *(const bf16x8*)&qhi[qr + 8 * g];
        qah[1] = *(const bf16x8*)&qhi[qr + 32 + 8 * g];
    }

    const int kr0 = t >> 3;
    const int db0 = (t & 7) * 8;
    const int sw0 = ((kr0 & 7) << 3);
    bf16x8 rkh, rvh;
    auto stage_load = [&](int ktg) {
        rkh = *(const bf16x8*)&khi[(size_t)(ktg + kr0) * DD + h * HD + db0];
        rvh = *(const bf16x8*)&vthi[(size_t)(h * HD + kr0) * NLK + ktg + db0];
    };
    auto stage_write = [&](int p) {
        const int i0 = kr0 * HD + (db0 ^ sw0);
        *(bf16x8*)&ksh[p][i0] = rkh;
        *(bf16x8*)&vth[p][i0] = rvh;
    };

    // packed fp16 bias prefetch: lane's 16 frag values = 2 x 16B coalesced
    const size_t btile0 = (size_t)(qt * 8 + wid) * 128;
    const int boff = lane * 16;
    u16x8 bp0, bp1;
    auto bias_pf = [&](int ktile) {
        const size_t ba = ((btile0 + (size_t)ktile) << 10) + boff;
        bp0 = *(const u16x8*)&biash[ba];
        bp1 = *(const u16x8*)&biash[ba + 8];
    };

    // ones B-fragment for the l = P x 1 row-sum MFMA
    bf16x8 ones;
#pragma unroll
    for (int i = 0; i < 8; ++i) ones[i] = (short)0x3F80;

    f32x4 acco[4];
    f32x4 lacc = (f32x4){0.f, 0.f, 0.f, 0.f};   // l for q = 4g + r
#pragma unroll
    for (int n = 0; n < 4; ++n) acco[n] = (f32x4){0.f, 0.f, 0.f, 0.f};
    float m_ = -1e30f;

    const int sA = ((g & 1) << 5) + cl;
    const int sB = sA + 16;
    const bool hi2 = (g >= 2);

    stage_load(k0);
    bias_pf(kc * NT);

    for (int it = 0; it < NT; ++it) {
        const int p = it & 1;
        stage_write(p);
        __syncthreads();
        if (it + 1 < NT) stage_load(k0 + (it + 1) * KT);

        // ---- C-in = bias fragment (mask + log2e prefolded) ----
        f32x4 sc[4];
#pragma unroll
        for (int j = 0; j < 4; ++j)
#pragma unroll
            for (int r = 0; r < 4; ++r) {
                const int i = j * 4 + r;
                sc[j][r] = h2f((i < 8) ? (unsigned short)bp0[i]
                                       : (unsigned short)bp1[i - 8]);
            }

        // ---- swapped QK^T accumulating onto bias ----
        __builtin_amdgcn_s_setprio(1);
#pragma unroll
        for (int j = 0; j < 4; ++j) {
            const int krow = (16 * j + cl) * HD;
#pragma unroll
            for (int s = 0; s < 2; ++s) {
                const bf16x8 kf = *(const bf16x8*)&ksh[p][krow + ((32 * s + 8 * g) ^ swc)];
                sc[j] = MFMA16(kf, qah[s], sc[j]);
            }
        }
        __builtin_amdgcn_s_setprio(0);

        if (it + 1 < NT) bias_pf(kc * NT + it + 1);

        // ---- in-register softmax with defer-max (no explicit row-sum) ----
        float tm = fmaxf(fmaxf(fmaxf(sc[0][0], sc[0][1]), fmaxf(sc[0][2], sc[0][3])),
                         fmaxf(fmaxf(sc[1][0], sc[1][1]), fmaxf(sc[1][2], sc[1][3])));
        tm = fmaxf(tm, fmaxf(fmaxf(fmaxf(sc[2][0], sc[2][1]), fmaxf(sc[2][2], sc[2][3])),
                             fmaxf(fmaxf(sc[3][0], sc[3][1]), fmaxf(sc[3][2], sc[3][3]))));
        tm = fmaxf(tm, __shfl_xor(tm, 16));
        tm = fmaxf(tm, __shfl_xor(tm, 32));
        if (!__all(tm - m_ <= 11.5f)) {
            const float mn = fmaxf(m_, tm);
            const float al = exp2f(m_ - mn);
            float alr[4];
#pragma unroll
            for (int r = 0; r < 4; ++r) alr[r] = __shfl(al, 4 * g + r);
#pragma unroll
            for (int n = 0; n < 4; ++n)
#pragma unroll
                for (int r = 0; r < 4; ++r) acco[n][r] *= alr[r];
#pragma unroll
            for (int r = 0; r < 4; ++r) lacc[r] *= alr[r];
            m_ = mn;
        }
#pragma unroll
        for (int j = 0; j < 4; ++j)
#pragma unroll
            for (int r = 0; r < 4; ++r)
                sc[j][r] = exp2f(sc[j][r] - m_);

        // ---- pack P (bf16 pairs) and redistribute to PV A-frags ----
        int Wp[4][2];
#pragma unroll
        for (int j = 0; j < 4; ++j) {
            Wp[j][0] = cvtpk(sc[j][0], sc[j][1]);
            Wp[j][1] = cvtpk(sc[j][2], sc[j][3]);
        }
        bf16x8 pah[2];
#pragma unroll
        for (int s = 0; s < 2; ++s) {
            const int a0 = __shfl(Wp[2 * s][0], sA);
            const int a1 = __shfl(Wp[2 * s][1], sA);
            const int b0 = __shfl(Wp[2 * s + 1][0], sA);
            const int b1 = __shfl(Wp[2 * s + 1][1], sA);
            const int c0 = __shfl(Wp[2 * s][0], sB);
            const int c1 = __shfl(Wp[2 * s][1], sB);
            const int d0 = __shfl(Wp[2 * s + 1][0], sB);
            const int d1 = __shfl(Wp[2 * s + 1][1], sB);
            int4 w;
            w.x = hi2 ? b0 : a0;
            w.y = hi2 ? b1 : a1;
            w.z = hi2 ? d0 : c0;
            w.w = hi2 ? d1 : c1;
            pah[s] = *(bf16x8*)&w;
        }

        // ---- PV + l-sum (both on matrix pipe) ----
        __builtin_amdgcn_s_setprio(1);
#pragma unroll
        for (int n = 0; n < 4; ++n) {
            const int drow = (16 * n + cl) * HD;
#pragma unroll
            for (int s = 0; s < 2; ++s) {
                const bf16x8 vh = *(const bf16x8*)&vth[p][drow + ((32 * s + 8 * g) ^ swc)];
                acco[n] = MFMA16(pah[s], vh, acco[n]);
            }
        }
        lacc = MFMA16(pah[0], ones, lacc);
        lacc = MFMA16(pah[1], ones, lacc);
        __builtin_amdgcn_s_setprio(0);
    }

    // epilogue: normalize by 1/lacc[r] (same-lane, q = 4g+r aligned)
    f32x4 linv;
#pragma unroll
    for (int r = 0; r < 4; ++r) linv[r] = 1.f / lacc[r];
#pragma unroll
    for (int r = 0; r < 4; ++r) {
        const int q = q0 + wid * 16 + 4 * g + r;
        const size_t base = ((size_t)(kc * NH + h) * NLQ + q) * HD;
#pragma unroll
        for (int n = 0; n < 4; ++n)
            macc[base + 16 * n + cl] = f2h(acco[n][r] * linv[r]);
    }
    // route l[q=cl] to the g==0 store lane (m_ is already per q=cl)
    {
        const int srcl = ((cl >> 2) << 4) + cl;
        const float lc0 = __shfl(lacc[0], srcl);
        const float lc1 = __shfl(lacc[1], srcl);
        const float lc2 = __shfl(lacc[2], srcl);
        const float lc3 = __shfl(lacc[3], srcl);
        const int rr = cl & 3;
        const float lq = rr == 0 ? lc0 : rr == 1 ? lc1 : rr == 2 ? lc2 : lc3;
        if (g == 0)
            mlb[(size_t)(kc * NH + h) * NLQ + q0 + wid * 16 + cl] = make_float2(m_, lq);
    }
}

// ---------------------------------------------------------------------------
// Combine: partials pre-normalized; weight = exp2(m_c - M) * l_c.
// ---------------------------------------------------------------------------
__global__ __launch_bounds__(256) void attn_combine(const unsigned short* __restrict__ macc,
                                                    const float2* __restrict__ mlb,
                                                    short* __restrict__ aohi,
                                                    short* __restrict__ aolo)
{
    const int row = blockIdx.x * 4 + (threadIdx.x >> 6);  // h*NLQ + q
    const int d   = threadIdx.x & 63;
    float m[NKC], l[NKC];
#pragma unroll
    for (int c = 0; c < NKC; ++c) {
        const float2 v = mlb[(size_t)c * NH * NLQ + row];
        m[c] = v.x; l[c] = v.y;
    }
    float M = m[0];
#pragma unroll
    for (int c = 1; c < NKC; ++c) M = fmaxf(M, m[c]);
    float w[NKC], L = 0.f;
#pragma unroll
    for (int c = 0; c < NKC; ++c) { w[c] = exp2f(m[c] - M) * l[c]; L += w[c]; }
    float s = 0.f;
#pragma unroll
    for (int c = 0; c < NKC; ++c)
        s += h2f(macc[((size_t)c * NH * NLQ + row) * HD + d]) * w[c];
    const float v = s / L;
    const int hh = row >> 11;
    const int q  = row & (NLQ - 1);
    const size_t o = (size_t)q * DD + hh * HD + d;
    const unsigned short hb = f2bf(v);
    aohi[o] = (short)hb;
    aolo[o] = (short)f2bf(v - bf2f(hb));
}

extern "C" void kernel_launch(void* const* d_in, const int* in_sizes, int n_in,
                              void* d_out, int out_size, void* d_ws, size_t ws_size,
                              hipStream_t stream)
{
    (void)in_sizes; (void)n_in; (void)out_size; (void)ws_size;
    const float* Q    = (const float*)d_in[0];
    const float* K    = (const float*)d_in[1];
    const float* V    = (const float*)d_in[2];
    const int*   mask = (const int*)d_in[3];
    const float* bias = (const float*)d_in[4];
    const float* Win  = (const float*)d_in[5];
    const float* bin  = (const float*)d_in[6];
    const float* Wout = (const float*)d_in[7];
    const float* bout = (const float*)d_in[8];
    float* out = (float*)d_out;

    // ---- workspace (~76 MB flat) ----
    short* qhi_  = (short*)d_ws;                                // 2 MB
    short* khi_  = qhi_  + (size_t)NLQ * DD;                    // 8 MB
    short* vthi_ = khi_  + (size_t)NLK * DD;                    // 8 MB
    short* whi_  = vthi_ + (size_t)NLK * DD;                    // 2 MB
    short* wlo_  = whi_  + (size_t)4 * DD * DD;                 // 2 MB
    unsigned short* biash_ = (unsigned short*)(wlo_ + (size_t)4 * DD * DD); // 32 MB
    unsigned short* macc_  = biash_ + (size_t)NLQ * NLK;        // 16.8 MB
    float2* ml_  = (float2*)(macc_ + (size_t)NKC * NH * NLQ * HD);  // 1 MB
    short* aohi_ = (short*)(ml_ + (size_t)NKC * NH * NLQ);      // 2 MB
    short* aolo_ = aohi_ + (size_t)NLQ * DD;                    // 2 MB

    const int CV = 256 * 4;

    // weights -> bf16 hi/lo ; bias+mask -> fp16 fragment pack (log2 units)
    cvt_hl<<<(3 * DD * DD + CV - 1) / CV, 256, 0, stream>>>(Win,  whi_, wlo_, 3 * DD * DD);
    cvt_hl<<<(DD * DD + CV - 1) / CV, 256, 0, stream>>>(Wout, whi_ + 3 * DD * DD, wlo_ + 3 * DD * DD, DD * DD);
    cvt_bias<<<(int)(((size_t)NLQ * NLK / 16) / 256), 256, 0, stream>>>(bias, mask, biash_);

    // fused QKV projection (576 blocks)
    gemm_qkvf<<<dim3(144, 4), 256, 0, stream>>>(Q, K, V, whi_, wlo_, bin, qhi_, khi_, vthi_);

    // attention (k-split NKC=8) + combine
    attn_mfma<<<dim3(NH * 16 * NKC), 512, 0, stream>>>(qhi_, khi_, vthi_, biash_, macc_, ml_);
    attn_combine<<<dim3(NH * NLQ / 4), 256, 0, stream>>>(macc_, ml_, aohi_, aolo_);

    // out projection (64x64 tiles, exact split path)
    gemm_out<<<dim3(NLQ / 64, DD / 64), 256, 0, stream>>>(aohi_, aolo_, whi_ + 3 * DD * DD, wlo_ + 3 * DD * DD,
                                                          bout, out);
}

// Round 12
// 165.378 us; speedup vs baseline: 3.1627x; 1.0021x over previous
//
#include <hip/hip_runtime.h>
#include <math.h>

#define DD 512
#define NH 8
#define HD 64
#define NLQ 2048
#define NLK 8192
#define LOG2E 1.4426950408889634f
#define SCQ (0.125f * LOG2E)

typedef __attribute__((ext_vector_type(8))) short bf16x8;
typedef __attribute__((ext_vector_type(8))) unsigned short u16x8;
typedef __attribute__((ext_vector_type(4))) short s16x4;
typedef __attribute__((ext_vector_type(4))) float f32x4;

#define MFMA16(a, b, c) __builtin_amdgcn_mfma_f32_16x16x32_bf16((a), (b), (c), 0, 0, 0)

__device__ __forceinline__ unsigned short f2bf(float x) {
    unsigned u = __builtin_bit_cast(unsigned, x);
    u += 0x7fffu + ((u >> 16) & 1u);
    return (unsigned short)(u >> 16);
}
__device__ __forceinline__ float bf2f(unsigned short h) {
    unsigned u = ((unsigned)h) << 16;
    return __builtin_bit_cast(float, u);
}
__device__ __forceinline__ unsigned short f2h(float x) {
    return __builtin_bit_cast(unsigned short, (_Float16)x);
}
__device__ __forceinline__ float h2f(unsigned short u) {
    return (float)__builtin_bit_cast(_Float16, u);
}
__device__ __forceinline__ int cvtpk(float a, float b) {
    int r;
    asm("v_cvt_pk_bf16_f32 %0, %1, %2" : "=v"(r) : "v"(a), "v"(b));
    return r;
}
__device__ __forceinline__ float max3f(float a, float b, float c) {
    return fmaxf(fmaxf(a, b), c);   // clang fuses to v_max3_f32
}

// ---------------------------------------------------------------------------
// fp32 -> bf16 hi/lo split (weights)
// ---------------------------------------------------------------------------
__global__ __launch_bounds__(256) void cvt_hl(const float* __restrict__ x,
                                              short* __restrict__ hi,
                                              short* __restrict__ lo, int n)
{
    const int i = (blockIdx.x * 256 + threadIdx.x) * 4;
    if (i >= n) return;
    const float4 v = *(const float4*)&x[i];
    const float a[4] = {v.x, v.y, v.z, v.w};
    s16x4 h, l;
#pragma unroll
    for (int j = 0; j < 4; ++j) {
        const unsigned short hh = f2bf(a[j]);
        h[j] = (short)hh;
        l[j] = (short)f2bf(a[j] - bf2f(hh));
    }
    *(s16x4*)&hi[i] = h;
    *(s16x4*)&lo[i] = l;
}

// ---------------------------------------------------------------------------
// bias+mask -> fp16 in log2 units, fragment-packed for swapped-QK order.
// ---------------------------------------------------------------------------
__global__ __launch_bounds__(256) void cvt_bias(const float* __restrict__ bias,
                                                const int* __restrict__ mask,
                                                unsigned short* __restrict__ bh)
{
    const int tid  = blockIdx.x * 256 + threadIdx.x;
    const int tile = tid >> 6;          // (Qg*128 + kt)
    const int l    = tid & 63;
    const int q    = (tile >> 7) * 16 + (l & 15);
    const int kb   = (tile & 127) * 64 + 4 * (l >> 4);
    u16x8 o0, o1;
#pragma unroll
    for (int j = 0; j < 4; ++j) {
        const float4 bv = *(const float4*)&bias[(size_t)q * NLK + kb + 16 * j];
        const int4   mv = *(const int4*)&mask[kb + 16 * j];
        const float a[4] = {bv.x, bv.y, bv.z, bv.w};
        const int   m[4] = {mv.x, mv.y, mv.z, mv.w};
#pragma unroll
        for (int r = 0; r < 4; ++r) {
            const float v = (a[r] - 10000.f * (float)m[r]) * LOG2E;
            const int idx = j * 4 + r;
            if (idx < 8) o0[idx] = f2h(v);
            else         o1[idx - 8] = f2h(v);
        }
    }
    const size_t base = ((size_t)tid) * 16;
    *(u16x8*)&bh[base] = o0;
    *(u16x8*)&bh[base + 8] = o1;
}

// ---------------------------------------------------------------------------
// FUSED QKV projection: one launch, 144 row-tiles x 4 col-tiles.
// ---------------------------------------------------------------------------
__global__ __launch_bounds__(256) void gemm_qkvf(const float* __restrict__ Q,
                                                 const float* __restrict__ K,
                                                 const float* __restrict__ V,
                                                 const short* __restrict__ Whi,
                                                 const short* __restrict__ Wlo,
                                                 const float* __restrict__ bin,
                                                 short* __restrict__ qhi,
                                                 short* __restrict__ khi,
                                                 short* __restrict__ vthi)
{
    __shared__ __align__(16) short XsH[128 * 40];
    __shared__ __align__(16) short WsH[128 * 40];
    __shared__ __align__(16) short WsL[128 * 40];

    const int bid = blockIdx.x;
    const float* X; const short *Wh, *Wl; const float* b; short* out;
    int r0; float scale; int tr;
    if (bid < 16)      { X = Q; r0 = bid * 128;        Wh = Whi;               Wl = Wlo;               b = bin;          out = qhi;  scale = SCQ; tr = 0; }
    else if (bid < 80) { X = K; r0 = (bid - 16) * 128; Wh = Whi + DD * DD;     Wl = Wlo + DD * DD;     b = bin + DD;     out = khi;  scale = 1.f; tr = 0; }
    else               { X = V; r0 = (bid - 80) * 128; Wh = Whi + 2 * DD * DD; Wl = Wlo + 2 * DD * DD; b = bin + 2 * DD; out = vthi; scale = 1.f; tr = 1; }
    const int o0 = blockIdx.y * 128;

    const int t    = threadIdx.x;
    const int wid  = t >> 6;
    const int lane = t & 63;
    const int g  = lane >> 4;
    const int c  = lane & 15;
    const int wr = wid >> 1;
    const int wc = wid & 1;
    const int srow = t >> 1;
    const int sk   = (t & 1) * 16;

    float4 xf[4];
    bf16x8 pwh[2], pwl[2];
    auto ld = [&](int kc) {
#pragma unroll
        for (int i = 0; i < 4; ++i)
            xf[i] = *(const float4*)&X[(size_t)(r0 + srow) * DD + kc + sk + 4 * i];
#pragma unroll
        for (int i = 0; i < 2; ++i) {
            pwh[i] = *(const bf16x8*)&Wh[(size_t)(o0 + srow) * DD + kc + sk + 8 * i];
            pwl[i] = *(const bf16x8*)&Wl[(size_t)(o0 + srow) * DD + kc + sk + 8 * i];
        }
    };
    auto st = [&]() {
#pragma unroll
        for (int i = 0; i < 2; ++i) {
            int4 w;
            w.x = cvtpk(xf[2 * i].x, xf[2 * i].y);
            w.y = cvtpk(xf[2 * i].z, xf[2 * i].w);
            w.z = cvtpk(xf[2 * i + 1].x, xf[2 * i + 1].y);
            w.w = cvtpk(xf[2 * i + 1].z, xf[2 * i + 1].w);
            *(int4*)&XsH[srow * 40 + sk + 8 * i] = w;
            *(bf16x8*)&WsH[srow * 40 + sk + 8 * i] = pwh[i];
            *(bf16x8*)&WsL[srow * 40 + sk + 8 * i] = pwl[i];
        }
    };

    f32x4 acc[4][4];
#pragma unroll
    for (int i = 0; i < 4; ++i)
#pragma unroll
        for (int j = 0; j < 4; ++j) acc[i][j] = (f32x4){0.f, 0.f, 0.f, 0.f};

    ld(0);
    for (int kc = 0; kc < DD; kc += 32) {
        __syncthreads();
        st();
        __syncthreads();
        if (kc + 32 < DD) ld(kc + 32);

        bf16x8 ah[4], bh[4], bl[4];
#pragma unroll
        for (int qg = 0; qg < 4; ++qg)
            ah[qg] = *(const bf16x8*)&XsH[(64 * wr + 16 * qg + c) * 40 + 8 * g];
#pragma unroll
        for (int og = 0; og < 4; ++og) {
            const int adr = (64 * wc + 16 * og + c) * 40 + 8 * g;
            bh[og] = *(const bf16x8*)&WsH[adr];
            bl[og] = *(const bf16x8*)&WsL[adr];
        }
#pragma unroll
        for (int qg = 0; qg < 4; ++qg)
#pragma unroll
            for (int og = 0; og < 4; ++og) {
                acc[qg][og] = MFMA16(ah[qg], bh[og], acc[qg][og]);
                acc[qg][og] = MFMA16(ah[qg], bl[og], acc[qg][og]);
            }
    }

#pragma unroll
    for (int qg = 0; qg < 4; ++qg)
#pragma unroll
        for (int og = 0; og < 4; ++og) {
            const int col = o0 + 64 * wc + 16 * og + c;
            const float bo = b[col];
#pragma unroll
            for (int r = 0; r < 4; ++r) {
                const int row = r0 + 64 * wr + 16 * qg + 4 * g + r;
                const float v = (acc[qg][og][r] + bo) * scale;
                if (tr) out[(size_t)col * NLK + row] = (short)f2bf(v);
                else    out[(size_t)row * DD + col]  = (short)f2bf(v);
            }
        }
}

// ---------------------------------------------------------------------------
// Out-projection: 64x64 tiles (256 blocks), X hi/lo, W hi/lo, 3-MFMA, f32 out.
// ---------------------------------------------------------------------------
__global__ __launch_bounds__(256) void gemm_out(const short* __restrict__ Xhi,
                                                const short* __restrict__ Xlo,
                                                const short* __restrict__ Whi,
                                                const short* __restrict__ Wlo,
                                                const float* __restrict__ b,
                                                float* __restrict__ Y)
{
    __shared__ __align__(16) short XsH[64 * 40];
    __shared__ __align__(16) short XsL[64 * 40];
    __shared__ __align__(16) short WsH[64 * 40];
    __shared__ __align__(16) short WsL[64 * 40];

    const int r0 = blockIdx.x * 64;
    const int o0 = blockIdx.y * 64;
    const int t    = threadIdx.x;
    const int wid  = t >> 6;
    const int lane = t & 63;
    const int g  = lane >> 4;
    const int c  = lane & 15;
    const int srow = t >> 2;
    const int sc8  = (t & 3) * 8;

    bf16x8 pxh, pxl, pwh, pwl;
    auto ld = [&](int kc) {
        pxh = *(const bf16x8*)&Xhi[(size_t)(r0 + srow) * DD + kc + sc8];
        pxl = *(const bf16x8*)&Xlo[(size_t)(r0 + srow) * DD + kc + sc8];
        pwh = *(const bf16x8*)&Whi[(size_t)(o0 + srow) * DD + kc + sc8];
        pwl = *(const bf16x8*)&Wlo[(size_t)(o0 + srow) * DD + kc + sc8];
    };
    auto st = [&]() {
        *(bf16x8*)&XsH[srow * 40 + sc8] = pxh;
        *(bf16x8*)&XsL[srow * 40 + sc8] = pxl;
        *(bf16x8*)&WsH[srow * 40 + sc8] = pwh;
        *(bf16x8*)&WsL[srow * 40 + sc8] = pwl;
    };

    f32x4 acc[4];
#pragma unroll
    for (int n = 0; n < 4; ++n) acc[n] = (f32x4){0.f, 0.f, 0.f, 0.f};

    ld(0);
    for (int kc = 0; kc < DD; kc += 32) {
        __syncthreads();
        st();
        __syncthreads();
        if (kc + 32 < DD) ld(kc + 32);

        bf16x8 ah, al, bh[4], bl[4];
        ah = *(const bf16x8*)&XsH[(wid * 16 + c) * 40 + 8 * g];
        al = *(const bf16x8*)&XsL[(wid * 16 + c) * 40 + 8 * g];
#pragma unroll
        for (int n = 0; n < 4; ++n) {
            const int adr = (16 * n + c) * 40 + 8 * g;
            bh[n] = *(const bf16x8*)&WsH[adr];
            bl[n] = *(const bf16x8*)&WsL[adr];
        }
#pragma unroll
        for (int n = 0; n < 4; ++n) {
            acc[n] = MFMA16(ah, bh[n], acc[n]);
            acc[n] = MFMA16(ah, bl[n], acc[n]);
            acc[n] = MFMA16(al, bh[n], acc[n]);
        }
    }

#pragma unroll
    for (int n = 0; n < 4; ++n) {
        const int col = o0 + 16 * n + c;
        const float bo = b[col];
#pragma unroll
        for (int r = 0; r < 4; ++r)
            Y[(size_t)(r0 + wid * 16 + 4 * g + r) * DD + col] = acc[n][r] + bo;
    }
}

// ---------------------------------------------------------------------------
// MFMA flash attention: swapped QK^T + in-register softmax.
// R12: all LDS read/write addresses precomputed as base pointers (XOR
// swizzle folded in); per-tile cost is 6 pointer-selects; every ds access
// uses a compile-time immediate offset. Global prefetch ptrs increment.
// max3 row-max tree. (512,4): VGPR cap 128 -- (512,8) spilled (R9).
// ---------------------------------------------------------------------------
#define QT 128
#define KT 64
#define NKC 8
#define CHUNK (NLK / NKC)
#define NT (CHUNK / KT)

__global__ __launch_bounds__(512, 4) void attn_mfma(const short* __restrict__ qhi,
                                                    const short* __restrict__ khi,
                                                    const short* __restrict__ vthi,
                                                    const unsigned short* __restrict__ biash,
                                                    unsigned short* __restrict__ macc,
                                                    float2* __restrict__ mlb)
{
    __shared__ __align__(16) short ksh[2 * KT * HD];
    __shared__ __align__(16) short vth[2 * KT * HD];

    const int id = blockIdx.x;          // h*128 + qt*8 + kc
    const int h  = id >> 7;
    const int qt = (id >> 3) & 15;
    const int kc = id & 7;
    const int q0 = qt * QT;
    const int k0 = kc * CHUNK;

    const int t    = threadIdx.x;
    const int wid  = t >> 6;
    const int lane = t & 63;
    const int g  = lane >> 4;
    const int cl = lane & 15;
    const int swc = ((cl & 7) << 3);

    bf16x8 qah[2];
    {
        const size_t qr = (size_t)(q0 + wid * 16 + cl) * DD + h * HD;
        qah[0] = *(const bf16x8*)&qhi[qr + 8 * g];
        qah[1] = *(const bf16x8*)&qhi[qr + 32 + 8 * g];
    }

    // ---- precomputed LDS pointers (loop-invariant; XOR swizzle folded) ----
    const int v0 = (8 * g) ^ swc;           // s=0 column offset
    const short* kbA0 = &ksh[cl * HD + v0];
    const short* kbB0 = &ksh[cl * HD + (v0 ^ 32)];
    const short* kbA1 = kbA0 + KT * HD;
    const short* kbB1 = kbB0 + KT * HD;
    const short* vbA0 = &vth[cl * HD + v0];
    const short* vbB0 = &vth[cl * HD + (v0 ^ 32)];
    const short* vbA1 = vbA0 + KT * HD;
    const short* vbB1 = vbB0 + KT * HD;

    const int kr0 = t >> 3;
    const int db0 = (t & 7) * 8;
    const int sw0 = ((kr0 & 7) << 3);
    short* wk0 = &ksh[kr0 * HD + (db0 ^ sw0)];
    short* wk1 = wk0 + KT * HD;
    short* wv0 = &vth[kr0 * HD + (db0 ^ sw0)];
    short* wv1 = wv0 + KT * HD;

    // ---- incrementing global prefetch pointers ----
    const short* kgp = khi + (size_t)(k0 + kr0) * DD + h * HD + db0;
    const short* vgp = vthi + (size_t)(h * HD + kr0) * NLK + k0 + db0;
    const unsigned short* bgp =
        biash + (((size_t)(qt * 8 + wid) * 128 + kc * NT) << 10) + lane * 16;

    bf16x8 rkh, rvh;
    u16x8 bp0, bp1;
    // prologue loads: tile 0
    rkh = *(const bf16x8*)kgp;  kgp += (size_t)KT * DD;
    rvh = *(const bf16x8*)vgp;  vgp += KT;
    bp0 = *(const u16x8*)bgp;
    bp1 = *(const u16x8*)(bgp + 8);  bgp += 1024;

    // ones B-fragment for the l = P x 1 row-sum MFMA
    bf16x8 ones;
#pragma unroll
    for (int i = 0; i < 8; ++i) ones[i] = (short)0x3F80;

    f32x4 acco[4];
    f32x4 lacc = (f32x4){0.f, 0.f, 0.f, 0.f};
#pragma unroll
    for (int n = 0; n < 4; ++n) acco[n] = (f32x4){0.f, 0.f, 0.f, 0.f};
    float m_ = -1e30f;

    const int sA = ((g & 1) << 5) + cl;
    const int sB = sA + 16;
    const bool hi2 = (g >= 2);

    for (int it = 0; it < NT; ++it) {
        const int p = it & 1;
        // per-tile pointer selects (cheap cndmask; all ds offsets immediate)
        const short* kA = p ? kbA1 : kbA0;
        const short* kB = p ? kbB1 : kbB0;
        const short* vA = p ? vbA1 : vbA0;
        const short* vB = p ? vbB1 : vbB0;
        short* wk = p ? wk1 : wk0;
        short* wv = p ? wv1 : wv0;

        *(bf16x8*)wk = rkh;
        *(bf16x8*)wv = rvh;
        __syncthreads();
        if (it + 1 < NT) {
            rkh = *(const bf16x8*)kgp;  kgp += (size_t)KT * DD;
            rvh = *(const bf16x8*)vgp;  vgp += KT;
        }

        // ---- C-in = bias fragment (mask + log2e prefolded) ----
        f32x4 sc[4];
#pragma unroll
        for (int j = 0; j < 4; ++j)
#pragma unroll
            for (int r = 0; r < 4; ++r) {
                const int i = j * 4 + r;
                sc[j][r] = h2f((i < 8) ? (unsigned short)bp0[i]
                                       : (unsigned short)bp1[i - 8]);
            }

        // ---- swapped QK^T accumulating onto bias ----
        __builtin_amdgcn_s_setprio(1);
#pragma unroll
        for (int j = 0; j < 4; ++j) {
            const bf16x8 kf0 = *(const bf16x8*)(kA + j * 16 * HD);
            const bf16x8 kf1 = *(const bf16x8*)(kB + j * 16 * HD);
            sc[j] = MFMA16(kf0, qah[0], sc[j]);
            sc[j] = MFMA16(kf1, qah[1], sc[j]);
        }
        __builtin_amdgcn_s_setprio(0);

        if (it + 1 < NT) {
            bp0 = *(const u16x8*)bgp;
            bp1 = *(const u16x8*)(bgp + 8);  bgp += 1024;
        }

        // ---- in-register softmax with defer-max (max3 trees) ----
        const float t0 = max3f(sc[0][0], sc[0][1], sc[0][2]);
        const float t1 = max3f(sc[0][3], sc[1][0], sc[1][1]);
        const float t2 = max3f(sc[1][2], sc[1][3], sc[2][0]);
        const float t3 = max3f(sc[2][1], sc[2][2], sc[2][3]);
        const float t4 = max3f(sc[3][0], sc[3][1], sc[3][2]);
        float tm = max3f(max3f(t0, t1, t2), max3f(t3, t4, sc[3][3]),
                         -1e30f);
        tm = fmaxf(tm, __shfl_xor(tm, 16));
        tm = fmaxf(tm, __shfl_xor(tm, 32));
        if (!__all(tm - m_ <= 11.5f)) {
            const float mn = fmaxf(m_, tm);
            const float al = exp2f(m_ - mn);
            float alr[4];
#pragma unroll
            for (int r = 0; r < 4; ++r) alr[r] = __shfl(al, 4 * g + r);
#pragma unroll
            for (int n = 0; n < 4; ++n)
#pragma unroll
                for (int r = 0; r < 4; ++r) acco[n][r] *= alr[r];
#pragma unroll
            for (int r = 0; r < 4; ++r) lacc[r] *= alr[r];
            m_ = mn;
        }
#pragma unroll
        for (int j = 0; j < 4; ++j)
#pragma unroll
            for (int r = 0; r < 4; ++r)
                sc[j][r] = exp2f(sc[j][r] - m_);

        // ---- pack P (bf16 pairs) and redistribute to PV A-frags ----
        int Wp[4][2];
#pragma unroll
        for (int j = 0; j < 4; ++j) {
            Wp[j][0] = cvtpk(sc[j][0], sc[j][1]);
            Wp[j][1] = cvtpk(sc[j][2], sc[j][3]);
        }
        bf16x8 pah[2];
#pragma unroll
        for (int s = 0; s < 2; ++s) {
            const int a0 = __shfl(Wp[2 * s][0], sA);
            const int a1 = __shfl(Wp[2 * s][1], sA);
            const int b0 = __shfl(Wp[2 * s + 1][0], sA);
            const int b1 = __shfl(Wp[2 * s + 1][1], sA);
            const int c0 = __shfl(Wp[2 * s][0], sB);
            const int c1 = __shfl(Wp[2 * s][1], sB);
            const int d0 = __shfl(Wp[2 * s + 1][0], sB);
            const int d1 = __shfl(Wp[2 * s + 1][1], sB);
            int4 w;
            w.x = hi2 ? b0 : a0;
            w.y = hi2 ? b1 : a1;
            w.z = hi2 ? d0 : c0;
            w.w = hi2 ? d1 : c1;
            pah[s] = *(bf16x8*)&w;
        }

        // ---- PV + l-sum (both on matrix pipe) ----
        __builtin_amdgcn_s_setprio(1);
#pragma unroll
        for (int n = 0; n < 4; ++n) {
            const bf16x8 vh0 = *(const bf16x8*)(vA + n * 16 * HD);
            const bf16x8 vh1 = *(const bf16x8*)(vB + n * 16 * HD);
            acco[n] = MFMA16(pah[0], vh0, acco[n]);
            acco[n] = MFMA16(pah[1], vh1, acco[n]);
        }
        lacc = MFMA16(pah[0], ones, lacc);
        lacc = MFMA16(pah[1], ones, lacc);
        __builtin_amdgcn_s_setprio(0);
    }

    // epilogue: normalize by 1/lacc[r] (same-lane, q = 4g+r aligned)
    f32x4 linv;
#pragma unroll
    for (int r = 0; r < 4; ++r) linv[r] = 1.f / lacc[r];
#pragma unroll
    for (int r = 0; r < 4; ++r) {
        const int q = q0 + wid * 16 + 4 * g + r;
        const size_t base = ((size_t)(kc * NH + h) * NLQ + q) * HD;
#pragma unroll
        for (int n = 0; n < 4; ++n)
            macc[base + 16 * n + cl] = f2h(acco[n][r] * linv[r]);
    }
    // route l[q=cl] to the g==0 store lane (m_ is already per q=cl)
    {
        const int srcl = ((cl >> 2) << 4) + cl;
        const float lc0 = __shfl(lacc[0], srcl);
        const float lc1 = __shfl(lacc[1], srcl);
        const float lc2 = __shfl(lacc[2], srcl);
        const float lc3 = __shfl(lacc[3], srcl);
        const int rr = cl & 3;
        const float lq = rr == 0 ? lc0 : rr == 1 ? lc1 : rr == 2 ? lc2 : lc3;
        if (g == 0)
            mlb[(size_t)(kc * NH + h) * NLQ + q0 + wid * 16 + cl] = make_float2(m_, lq);
    }
}

// ---------------------------------------------------------------------------
// Combine: partials pre-normalized; weight = exp2(m_c - M) * l_c.
// ---------------------------------------------------------------------------
__global__ __launch_bounds__(256) void attn_combine(const unsigned short* __restrict__ macc,
                                                    const float2* __restrict__ mlb,
                                                    short* __restrict__ aohi,
                                                    short* __restrict__ aolo)
{
    const int row = blockIdx.x * 4 + (threadIdx.x >> 6);  // h*NLQ + q
    const int d   = threadIdx.x & 63;
    float m[NKC], l[NKC];
#pragma unroll
    for (int c = 0; c < NKC; ++c) {
        const float2 v = mlb[(size_t)c * NH * NLQ + row];
        m[c] = v.x; l[c] = v.y;
    }
    float M = m[0];
#pragma unroll
    for (int c = 1; c < NKC; ++c) M = fmaxf(M, m[c]);
    float w[NKC], L = 0.f;
#pragma unroll
    for (int c = 0; c < NKC; ++c) { w[c] = exp2f(m[c] - M) * l[c]; L += w[c]; }
    float s = 0.f;
#pragma unroll
    for (int c = 0; c < NKC; ++c)
        s += h2f(macc[((size_t)c * NH * NLQ + row) * HD + d]) * w[c];
    const float v = s / L;
    const int hh = row >> 11;
    const int q  = row & (NLQ - 1);
    const size_t o = (size_t)q * DD + hh * HD + d;
    const unsigned short hb = f2bf(v);
    aohi[o] = (short)hb;
    aolo[o] = (short)f2bf(v - bf2f(hb));
}

extern "C" void kernel_launch(void* const* d_in, const int* in_sizes, int n_in,
                              void* d_out, int out_size, void* d_ws, size_t ws_size,
                              hipStream_t stream)
{
    (void)in_sizes; (void)n_in; (void)out_size; (void)ws_size;
    const float* Q    = (const float*)d_in[0];
    const float* K    = (const float*)d_in[1];
    const float* V    = (const float*)d_in[2];
    const int*   mask = (const int*)d_in[3];
    const float* bias = (const float*)d_in[4];
    const float* Win  = (const float*)d_in[5];
    const float* bin  = (const float*)d_in[6];
    const float* Wout = (const float*)d_in[7];
    const float* bout = (const float*)d_in[8];
    float* out = (float*)d_out;

    // ---- workspace (~76 MB flat) ----
    short* qhi_  = (short*)d_ws;                                // 2 MB
    short* khi_  = qhi_  + (size_t)NLQ * DD;                    // 8 MB
    short* vthi_ = khi_  + (size_t)NLK * DD;                    // 8 MB
    short* whi_  = vthi_ + (size_t)NLK * DD;                    // 2 MB
    short* wlo_  = whi_  + (size_t)4 * DD * DD;                 // 2 MB
    unsigned short* biash_ = (unsigned short*)(wlo_ + (size_t)4 * DD * DD); // 32 MB
    unsigned short* macc_  = biash_ + (size_t)NLQ * NLK;        // 16.8 MB
    float2* ml_  = (float2*)(macc_ + (size_t)NKC * NH * NLQ * HD);  // 1 MB
    short* aohi_ = (short*)(ml_ + (size_t)NKC * NH * NLQ);      // 2 MB
    short* aolo_ = aohi_ + (size_t)NLQ * DD;                    // 2 MB

    const int CV = 256 * 4;

    // weights -> bf16 hi/lo ; bias+mask -> fp16 fragment pack (log2 units)
    cvt_hl<<<(3 * DD * DD + CV - 1) / CV, 256, 0, stream>>>(Win,  whi_, wlo_, 3 * DD * DD);
    cvt_hl<<<(DD * DD + CV - 1) / CV, 256, 0, stream>>>(Wout, whi_ + 3 * DD * DD, wlo_ + 3 * DD * DD, DD * DD);
    cvt_bias<<<(int)(((size_t)NLQ * NLK / 16) / 256), 256, 0, stream>>>(bias, mask, biash_);

    // fused QKV projection (576 blocks)
    gemm_qkvf<<<dim3(144, 4), 256, 0, stream>>>(Q, K, V, whi_, wlo_, bin, qhi_, khi_, vthi_);

    // attention (k-split NKC=8) + combine
    attn_mfma<<<dim3(NH * 16 * NKC), 512, 0, stream>>>(qhi_, khi_, vthi_, biash_, macc_, ml_);
    attn_combine<<<dim3(NH * NLQ / 4), 256, 0, stream>>>(macc_, ml_, aohi_, aolo_);

    // out projection (64x64 tiles, exact split path)
    gemm_out<<<dim3(NLQ / 64, DD / 64), 256, 0, stream>>>(aohi_, aolo_, whi_ + 3 * DD * DD, wlo_ + 3 * DD * DD,
                                                          bout, out);
}

// Round 13
// 153.979 us; speedup vs baseline: 3.3968x; 1.0740x over previous
//
#include <hip/hip_runtime.h>
#include <math.h>

#define DD 512
#define NH 8
#define HD 64
#define NLQ 2048
#define NLK 8192
#define LOG2E 1.4426950408889634f
#define SCQ (0.125f * LOG2E)

typedef __attribute__((ext_vector_type(8))) short bf16x8;
typedef __attribute__((ext_vector_type(8))) unsigned short u16x8;
typedef __attribute__((ext_vector_type(4))) float f32x4;

#define MFMA16(a, b, c) __builtin_amdgcn_mfma_f32_16x16x32_bf16((a), (b), (c), 0, 0, 0)

__device__ __forceinline__ unsigned short f2bf(float x) {
    unsigned u = __builtin_bit_cast(unsigned, x);
    u += 0x7fffu + ((u >> 16) & 1u);
    return (unsigned short)(u >> 16);
}
__device__ __forceinline__ float bf2f(unsigned short h) {
    unsigned u = ((unsigned)h) << 16;
    return __builtin_bit_cast(float, u);
}
__device__ __forceinline__ unsigned short f2h(float x) {
    return __builtin_bit_cast(unsigned short, (_Float16)x);
}
__device__ __forceinline__ float h2f(unsigned short u) {
    return (float)__builtin_bit_cast(_Float16, u);
}
__device__ __forceinline__ int cvtpk(float a, float b) {
    int r;
    asm("v_cvt_pk_bf16_f32 %0, %1, %2" : "=v"(r) : "v"(a), "v"(b));
    return r;
}
__device__ __forceinline__ float max3f(float a, float b, float c) {
    return fmaxf(fmaxf(a, b), c);   // clang fuses to v_max3_f32
}
// bf2f of the low/high bf16 halves of a cvtpk-packed int
__device__ __forceinline__ float lobf(int w) {
    return __builtin_bit_cast(float, w << 16);
}
__device__ __forceinline__ float hibf(int w) {
    return __builtin_bit_cast(float, (int)(w & 0xffff0000));
}

// ---------------------------------------------------------------------------
// PREP (one launch, block-range fused):
//   blocks [0, 576):    QKV projection. bx=bid%144: <16 Q | <80 K | else V(tr).
//                       X f32 direct; W f32 -> hi/lo split IN STAGING.
//   blocks [576, 4672): bias+mask -> fp16 log2-units fragment pack.
// ---------------------------------------------------------------------------
#define NPROJ 576

__global__ __launch_bounds__(256) void prep(const float* __restrict__ Q,
                                            const float* __restrict__ K,
                                            const float* __restrict__ V,
                                            const float* __restrict__ Win,
                                            const float* __restrict__ bin,
                                            const float* __restrict__ bias,
                                            const int* __restrict__ mask,
                                            short* __restrict__ qhi,
                                            short* __restrict__ khi,
                                            short* __restrict__ vthi,
                                            unsigned short* __restrict__ bh)
{
    __shared__ __align__(16) short XsH[128 * 40];
    __shared__ __align__(16) short WsH[128 * 40];
    __shared__ __align__(16) short WsL[128 * 40];

    const int bid = blockIdx.x;
    if (bid >= NPROJ) {
        // ---- bias pack path (grid-fused; no LDS use) ----
        const int tid  = (bid - NPROJ) * 256 + threadIdx.x;
        const int tile = tid >> 6;          // (Qg*128 + kt)
        const int l    = tid & 63;
        const int q    = (tile >> 7) * 16 + (l & 15);
        const int kb   = (tile & 127) * 64 + 4 * (l >> 4);
        u16x8 o0v, o1v;
#pragma unroll
        for (int j = 0; j < 4; ++j) {
            const float4 bv = *(const float4*)&bias[(size_t)q * NLK + kb + 16 * j];
            const int4   mv = *(const int4*)&mask[kb + 16 * j];
            const float a[4] = {bv.x, bv.y, bv.z, bv.w};
            const int   m[4] = {mv.x, mv.y, mv.z, mv.w};
#pragma unroll
            for (int r = 0; r < 4; ++r) {
                const float v = (a[r] - 10000.f * (float)m[r]) * LOG2E;
                const int idx = j * 4 + r;
                if (idx < 8) o0v[idx] = f2h(v);
                else         o1v[idx - 8] = f2h(v);
            }
        }
        const size_t base = ((size_t)tid) * 16;
        *(u16x8*)&bh[base] = o0v;
        *(u16x8*)&bh[base + 8] = o1v;
        return;
    }

    // ---- QKV projection path ----
    const int o0 = (bid / 144) * 128;
    const int bx = bid % 144;
    const float* X; const float* Wf; const float* b; short* out;
    int r0; float scale; int tr;
    if (bx < 16)      { X = Q; r0 = bx * 128;        Wf = Win;               b = bin;          out = qhi;  scale = SCQ; tr = 0; }
    else if (bx < 80) { X = K; r0 = (bx - 16) * 128; Wf = Win + DD * DD;     b = bin + DD;     out = khi;  scale = 1.f; tr = 0; }
    else              { X = V; r0 = (bx - 80) * 128; Wf = Win + 2 * DD * DD; b = bin + 2 * DD; out = vthi; scale = 1.f; tr = 1; }

    const int t    = threadIdx.x;
    const int wid  = t >> 6;
    const int lane = t & 63;
    const int g  = lane >> 4;
    const int c  = lane & 15;
    const int wr = wid >> 1;
    const int wc = wid & 1;
    const int srow = t >> 1;
    const int sk   = (t & 1) * 16;

    float4 xf[4], wf[4];
    auto ld = [&](int kc) {
#pragma unroll
        for (int i = 0; i < 4; ++i) {
            xf[i] = *(const float4*)&X[(size_t)(r0 + srow) * DD + kc + sk + 4 * i];
            wf[i] = *(const float4*)&Wf[(size_t)(o0 + srow) * DD + kc + sk + 4 * i];
        }
    };
    auto st = [&]() {
#pragma unroll
        for (int i = 0; i < 2; ++i) {
            // X: hi only
            int4 xw;
            xw.x = cvtpk(xf[2 * i].x, xf[2 * i].y);
            xw.y = cvtpk(xf[2 * i].z, xf[2 * i].w);
            xw.z = cvtpk(xf[2 * i + 1].x, xf[2 * i + 1].y);
            xw.w = cvtpk(xf[2 * i + 1].z, xf[2 * i + 1].w);
            *(int4*)&XsH[srow * 40 + sk + 8 * i] = xw;
            // W: hi + lo split in registers (bitwise == old cvt_hl pass)
            const float4 a = wf[2 * i], bb = wf[2 * i + 1];
            int4 hw;
            hw.x = cvtpk(a.x, a.y);
            hw.y = cvtpk(a.z, a.w);
            hw.z = cvtpk(bb.x, bb.y);
            hw.w = cvtpk(bb.z, bb.w);
            int4 lw;
            lw.x = cvtpk(a.x - lobf(hw.x), a.y - hibf(hw.x));
            lw.y = cvtpk(a.z - lobf(hw.y), a.w - hibf(hw.y));
            lw.z = cvtpk(bb.x - lobf(hw.z), bb.y - hibf(hw.z));
            lw.w = cvtpk(bb.z - lobf(hw.w), bb.w - hibf(hw.w));
            *(int4*)&WsH[srow * 40 + sk + 8 * i] = hw;
            *(int4*)&WsL[srow * 40 + sk + 8 * i] = lw;
        }
    };

    f32x4 acc[4][4];
#pragma unroll
    for (int i = 0; i < 4; ++i)
#pragma unroll
        for (int j = 0; j < 4; ++j) acc[i][j] = (f32x4){0.f, 0.f, 0.f, 0.f};

    ld(0);
    for (int kc = 0; kc < DD; kc += 32) {
        __syncthreads();
        st();
        __syncthreads();
        if (kc + 32 < DD) ld(kc + 32);

        bf16x8 ah[4], bhf[4], blf[4];
#pragma unroll
        for (int qg = 0; qg < 4; ++qg)
            ah[qg] = *(const bf16x8*)&XsH[(64 * wr + 16 * qg + c) * 40 + 8 * g];
#pragma unroll
        for (int og = 0; og < 4; ++og) {
            const int adr = (64 * wc + 16 * og + c) * 40 + 8 * g;
            bhf[og] = *(const bf16x8*)&WsH[adr];
            blf[og] = *(const bf16x8*)&WsL[adr];
        }
#pragma unroll
        for (int qg = 0; qg < 4; ++qg)
#pragma unroll
            for (int og = 0; og < 4; ++og) {
                acc[qg][og] = MFMA16(ah[qg], bhf[og], acc[qg][og]);
                acc[qg][og] = MFMA16(ah[qg], blf[og], acc[qg][og]);
            }
    }

#pragma unroll
    for (int qg = 0; qg < 4; ++qg)
#pragma unroll
        for (int og = 0; og < 4; ++og) {
            const int col = o0 + 64 * wc + 16 * og + c;
            const float bo = b[col];
#pragma unroll
            for (int r = 0; r < 4; ++r) {
                const int row = r0 + 64 * wr + 16 * qg + 4 * g + r;
                const float v = (acc[qg][og][r] + bo) * scale;
                if (tr) out[(size_t)col * NLK + row] = (short)f2bf(v);
                else    out[(size_t)row * DD + col]  = (short)f2bf(v);
            }
        }
}

// ---------------------------------------------------------------------------
// Out-projection: 64x64 tiles (256 blocks), X hi/lo (from combine),
// W f32 -> hi/lo split in staging, 3-MFMA, f32 out.
// ---------------------------------------------------------------------------
__global__ __launch_bounds__(256) void gemm_out(const short* __restrict__ Xhi,
                                                const short* __restrict__ Xlo,
                                                const float* __restrict__ Wf,
                                                const float* __restrict__ b,
                                                float* __restrict__ Y)
{
    __shared__ __align__(16) short XsH[64 * 40];
    __shared__ __align__(16) short XsL[64 * 40];
    __shared__ __align__(16) short WsH[64 * 40];
    __shared__ __align__(16) short WsL[64 * 40];

    const int r0 = blockIdx.x * 64;
    const int o0 = blockIdx.y * 64;
    const int t    = threadIdx.x;
    const int wid  = t >> 6;
    const int lane = t & 63;
    const int g  = lane >> 4;
    const int c  = lane & 15;
    const int srow = t >> 2;
    const int sc8  = (t & 3) * 8;

    bf16x8 pxh, pxl;
    float4 wf0, wf1;
    auto ld = [&](int kc) {
        pxh = *(const bf16x8*)&Xhi[(size_t)(r0 + srow) * DD + kc + sc8];
        pxl = *(const bf16x8*)&Xlo[(size_t)(r0 + srow) * DD + kc + sc8];
        wf0 = *(const float4*)&Wf[(size_t)(o0 + srow) * DD + kc + sc8];
        wf1 = *(const float4*)&Wf[(size_t)(o0 + srow) * DD + kc + sc8 + 4];
    };
    auto st = [&]() {
        *(bf16x8*)&XsH[srow * 40 + sc8] = pxh;
        *(bf16x8*)&XsL[srow * 40 + sc8] = pxl;
        int4 hw;
        hw.x = cvtpk(wf0.x, wf0.y);
        hw.y = cvtpk(wf0.z, wf0.w);
        hw.z = cvtpk(wf1.x, wf1.y);
        hw.w = cvtpk(wf1.z, wf1.w);
        int4 lw;
        lw.x = cvtpk(wf0.x - lobf(hw.x), wf0.y - hibf(hw.x));
        lw.y = cvtpk(wf0.z - lobf(hw.y), wf0.w - hibf(hw.y));
        lw.z = cvtpk(wf1.x - lobf(hw.z), wf1.y - hibf(hw.z));
        lw.w = cvtpk(wf1.z - lobf(hw.w), wf1.w - hibf(hw.w));
        *(int4*)&WsH[srow * 40 + sc8] = hw;
        *(int4*)&WsL[srow * 40 + sc8] = lw;
    };

    f32x4 acc[4];
#pragma unroll
    for (int n = 0; n < 4; ++n) acc[n] = (f32x4){0.f, 0.f, 0.f, 0.f};

    ld(0);
    for (int kc = 0; kc < DD; kc += 32) {
        __syncthreads();
        st();
        __syncthreads();
        if (kc + 32 < DD) ld(kc + 32);

        bf16x8 ah, al, bh[4], bl[4];
        ah = *(const bf16x8*)&XsH[(wid * 16 + c) * 40 + 8 * g];
        al = *(const bf16x8*)&XsL[(wid * 16 + c) * 40 + 8 * g];
#pragma unroll
        for (int n = 0; n < 4; ++n) {
            const int adr = (16 * n + c) * 40 + 8 * g;
            bh[n] = *(const bf16x8*)&WsH[adr];
            bl[n] = *(const bf16x8*)&WsL[adr];
        }
#pragma unroll
        for (int n = 0; n < 4; ++n) {
            acc[n] = MFMA16(ah, bh[n], acc[n]);
            acc[n] = MFMA16(ah, bl[n], acc[n]);
            acc[n] = MFMA16(al, bh[n], acc[n]);
        }
    }

#pragma unroll
    for (int n = 0; n < 4; ++n) {
        const int col = o0 + 16 * n + c;
        const float bo = b[col];
#pragma unroll
        for (int r = 0; r < 4; ++r)
            Y[(size_t)(r0 + wid * 16 + 4 * g + r) * DD + col] = acc[n][r] + bo;
    }
}

// ---------------------------------------------------------------------------
// MFMA flash attention (R12 body, unchanged): swapped QK^T, in-register
// softmax, bias as MFMA C-in, l = P*ones MFMA, precomputed LDS pointers,
// defer-max, setprio. (512,4): VGPR cap 128 -- (512,8) spilled (R9).
// ---------------------------------------------------------------------------
#define QT 128
#define KT 64
#define NKC 8
#define CHUNK (NLK / NKC)
#define NT (CHUNK / KT)

__global__ __launch_bounds__(512, 4) void attn_mfma(const short* __restrict__ qhi,
                                                    const short* __restrict__ khi,
                                                    const short* __restrict__ vthi,
                                                    const unsigned short* __restrict__ biash,
                                                    unsigned short* __restrict__ macc,
                                                    float2* __restrict__ mlb)
{
    __shared__ __align__(16) short ksh[2 * KT * HD];
    __shared__ __align__(16) short vth[2 * KT * HD];

    const int id = blockIdx.x;          // h*128 + qt*8 + kc
    const int h  = id >> 7;
    const int qt = (id >> 3) & 15;
    const int kc = id & 7;
    const int q0 = qt * QT;
    const int k0 = kc * CHUNK;

    const int t    = threadIdx.x;
    const int wid  = t >> 6;
    const int lane = t & 63;
    const int g  = lane >> 4;
    const int cl = lane & 15;
    const int swc = ((cl & 7) << 3);

    bf16x8 qah[2];
    {
        const size_t qr = (size_t)(q0 + wid * 16 + cl) * DD + h * HD;
        qah[0] = *(const bf16x8*)&qhi[qr + 8 * g];
        qah[1] = *(const bf16x8*)&qhi[qr + 32 + 8 * g];
    }

    const int v0 = (8 * g) ^ swc;
    const short* kbA0 = &ksh[cl * HD + v0];
    const short* kbB0 = &ksh[cl * HD + (v0 ^ 32)];
    const short* kbA1 = kbA0 + KT * HD;
    const short* kbB1 = kbB0 + KT * HD;
    const short* vbA0 = &vth[cl * HD + v0];
    const short* vbB0 = &vth[cl * HD + (v0 ^ 32)];
    const short* vbA1 = vbA0 + KT * HD;
    const short* vbB1 = vbB0 + KT * HD;

    const int kr0 = t >> 3;
    const int db0 = (t & 7) * 8;
    const int sw0 = ((kr0 & 7) << 3);
    short* wk0 = &ksh[kr0 * HD + (db0 ^ sw0)];
    short* wk1 = wk0 + KT * HD;
    short* wv0 = &vth[kr0 * HD + (db0 ^ sw0)];
    short* wv1 = wv0 + KT * HD;

    const short* kgp = khi + (size_t)(k0 + kr0) * DD + h * HD + db0;
    const short* vgp = vthi + (size_t)(h * HD + kr0) * NLK + k0 + db0;
    const unsigned short* bgp =
        biash + (((size_t)(qt * 8 + wid) * 128 + kc * NT) << 10) + lane * 16;

    bf16x8 rkh, rvh;
    u16x8 bp0, bp1;
    rkh = *(const bf16x8*)kgp;  kgp += (size_t)KT * DD;
    rvh = *(const bf16x8*)vgp;  vgp += KT;
    bp0 = *(const u16x8*)bgp;
    bp1 = *(const u16x8*)(bgp + 8);  bgp += 1024;

    bf16x8 ones;
#pragma unroll
    for (int i = 0; i < 8; ++i) ones[i] = (short)0x3F80;

    f32x4 acco[4];
    f32x4 lacc = (f32x4){0.f, 0.f, 0.f, 0.f};
#pragma unroll
    for (int n = 0; n < 4; ++n) acco[n] = (f32x4){0.f, 0.f, 0.f, 0.f};
    float m_ = -1e30f;

    const int sA = ((g & 1) << 5) + cl;
    const int sB = sA + 16;
    const bool hi2 = (g >= 2);

    for (int it = 0; it < NT; ++it) {
        const int p = it & 1;
        const short* kA = p ? kbA1 : kbA0;
        const short* kB = p ? kbB1 : kbB0;
        const short* vA = p ? vbA1 : vbA0;
        const short* vB = p ? vbB1 : vbB0;
        short* wk = p ? wk1 : wk0;
        short* wv = p ? wv1 : wv0;

        *(bf16x8*)wk = rkh;
        *(bf16x8*)wv = rvh;
        __syncthreads();
        if (it + 1 < NT) {
            rkh = *(const bf16x8*)kgp;  kgp += (size_t)KT * DD;
            rvh = *(const bf16x8*)vgp;  vgp += KT;
        }

        f32x4 sc[4];
#pragma unroll
        for (int j = 0; j < 4; ++j)
#pragma unroll
            for (int r = 0; r < 4; ++r) {
                const int i = j * 4 + r;
                sc[j][r] = h2f((i < 8) ? (unsigned short)bp0[i]
                                       : (unsigned short)bp1[i - 8]);
            }

        __builtin_amdgcn_s_setprio(1);
#pragma unroll
        for (int j = 0; j < 4; ++j) {
            const bf16x8 kf0 = *(const bf16x8*)(kA + j * 16 * HD);
            const bf16x8 kf1 = *(const bf16x8*)(kB + j * 16 * HD);
            sc[j] = MFMA16(kf0, qah[0], sc[j]);
            sc[j] = MFMA16(kf1, qah[1], sc[j]);
        }
        __builtin_amdgcn_s_setprio(0);

        if (it + 1 < NT) {
            bp0 = *(const u16x8*)bgp;
            bp1 = *(const u16x8*)(bgp + 8);  bgp += 1024;
        }

        const float t0 = max3f(sc[0][0], sc[0][1], sc[0][2]);
        const float t1 = max3f(sc[0][3], sc[1][0], sc[1][1]);
        const float t2 = max3f(sc[1][2], sc[1][3], sc[2][0]);
        const float t3 = max3f(sc[2][1], sc[2][2], sc[2][3]);
        const float t4 = max3f(sc[3][0], sc[3][1], sc[3][2]);
        float tm = max3f(max3f(t0, t1, t2), max3f(t3, t4, sc[3][3]),
                         -1e30f);
        tm = fmaxf(tm, __shfl_xor(tm, 16));
        tm = fmaxf(tm, __shfl_xor(tm, 32));
        if (!__all(tm - m_ <= 11.5f)) {
            const float mn = fmaxf(m_, tm);
            const float al = exp2f(m_ - mn);
            float alr[4];
#pragma unroll
            for (int r = 0; r < 4; ++r) alr[r] = __shfl(al, 4 * g + r);
#pragma unroll
            for (int n = 0; n < 4; ++n)
#pragma unroll
                for (int r = 0; r < 4; ++r) acco[n][r] *= alr[r];
#pragma unroll
            for (int r = 0; r < 4; ++r) lacc[r] *= alr[r];
            m_ = mn;
        }
#pragma unroll
        for (int j = 0; j < 4; ++j)
#pragma unroll
            for (int r = 0; r < 4; ++r)
                sc[j][r] = exp2f(sc[j][r] - m_);

        int Wp[4][2];
#pragma unroll
        for (int j = 0; j < 4; ++j) {
            Wp[j][0] = cvtpk(sc[j][0], sc[j][1]);
            Wp[j][1] = cvtpk(sc[j][2], sc[j][3]);
        }
        bf16x8 pah[2];
#pragma unroll
        for (int s = 0; s < 2; ++s) {
            const int a0 = __shfl(Wp[2 * s][0], sA);
            const int a1 = __shfl(Wp[2 * s][1], sA);
            const int b0 = __shfl(Wp[2 * s + 1][0], sA);
            const int b1 = __shfl(Wp[2 * s + 1][1], sA);
            const int c0 = __shfl(Wp[2 * s][0], sB);
            const int c1 = __shfl(Wp[2 * s][1], sB);
            const int d0 = __shfl(Wp[2 * s + 1][0], sB);
            const int d1 = __shfl(Wp[2 * s + 1][1], sB);
            int4 w;
            w.x = hi2 ? b0 : a0;
            w.y = hi2 ? b1 : a1;
            w.z = hi2 ? d0 : c0;
            w.w = hi2 ? d1 : c1;
            pah[s] = *(bf16x8*)&w;
        }

        __builtin_amdgcn_s_setprio(1);
#pragma unroll
        for (int n = 0; n < 4; ++n) {
            const bf16x8 vh0 = *(const bf16x8*)(vA + n * 16 * HD);
            const bf16x8 vh1 = *(const bf16x8*)(vB + n * 16 * HD);
            acco[n] = MFMA16(pah[0], vh0, acco[n]);
            acco[n] = MFMA16(pah[1], vh1, acco[n]);
        }
        lacc = MFMA16(pah[0], ones, lacc);
        lacc = MFMA16(pah[1], ones, lacc);
        __builtin_amdgcn_s_setprio(0);
    }

    f32x4 linv;
#pragma unroll
    for (int r = 0; r < 4; ++r) linv[r] = 1.f / lacc[r];
#pragma unroll
    for (int r = 0; r < 4; ++r) {
        const int q = q0 + wid * 16 + 4 * g + r;
        const size_t base = ((size_t)(kc * NH + h) * NLQ + q) * HD;
#pragma unroll
        for (int n = 0; n < 4; ++n)
            macc[base + 16 * n + cl] = f2h(acco[n][r] * linv[r]);
    }
    {
        const int srcl = ((cl >> 2) << 4) + cl;
        const float lc0 = __shfl(lacc[0], srcl);
        const float lc1 = __shfl(lacc[1], srcl);
        const float lc2 = __shfl(lacc[2], srcl);
        const float lc3 = __shfl(lacc[3], srcl);
        const int rr = cl & 3;
        const float lq = rr == 0 ? lc0 : rr == 1 ? lc1 : rr == 2 ? lc2 : lc3;
        if (g == 0)
            mlb[(size_t)(kc * NH + h) * NLQ + q0 + wid * 16 + cl] = make_float2(m_, lq);
    }
}

// ---------------------------------------------------------------------------
// Combine: partials pre-normalized; weight = exp2(m_c - M) * l_c.
// ---------------------------------------------------------------------------
__global__ __launch_bounds__(256) void attn_combine(const unsigned short* __restrict__ macc,
                                                    const float2* __restrict__ mlb,
                                                    short* __restrict__ aohi,
                                                    short* __restrict__ aolo)
{
    const int row = blockIdx.x * 4 + (threadIdx.x >> 6);  // h*NLQ + q
    const int d   = threadIdx.x & 63;
    float m[NKC], l[NKC];
#pragma unroll
    for (int c = 0; c < NKC; ++c) {
        const float2 v = mlb[(size_t)c * NH * NLQ + row];
        m[c] = v.x; l[c] = v.y;
    }
    float M = m[0];
#pragma unroll
    for (int c = 1; c < NKC; ++c) M = fmaxf(M, m[c]);
    float w[NKC], L = 0.f;
#pragma unroll
    for (int c = 0; c < NKC; ++c) { w[c] = exp2f(m[c] - M) * l[c]; L += w[c]; }
    float s = 0.f;
#pragma unroll
    for (int c = 0; c < NKC; ++c)
        s += h2f(macc[((size_t)c * NH * NLQ + row) * HD + d]) * w[c];
    const float v = s / L;
    const int hh = row >> 11;
    const int q  = row & (NLQ - 1);
    const size_t o = (size_t)q * DD + hh * HD + d;
    const unsigned short hb = f2bf(v);
    aohi[o] = (short)hb;
    aolo[o] = (short)f2bf(v - bf2f(hb));
}

extern "C" void kernel_launch(void* const* d_in, const int* in_sizes, int n_in,
                              void* d_out, int out_size, void* d_ws, size_t ws_size,
                              hipStream_t stream)
{
    (void)in_sizes; (void)n_in; (void)out_size; (void)ws_size;
    const float* Q    = (const float*)d_in[0];
    const float* K    = (const float*)d_in[1];
    const float* V    = (const float*)d_in[2];
    const int*   mask = (const int*)d_in[3];
    const float* bias = (const float*)d_in[4];
    const float* Win  = (const float*)d_in[5];
    const float* bin  = (const float*)d_in[6];
    const float* Wout = (const float*)d_in[7];
    const float* bout = (const float*)d_in[8];
    float* out = (float*)d_out;

    // ---- workspace (~72 MB flat) ----
    short* qhi_  = (short*)d_ws;                                // 2 MB
    short* khi_  = qhi_  + (size_t)NLQ * DD;                    // 8 MB
    short* vthi_ = khi_  + (size_t)NLK * DD;                    // 8 MB
    unsigned short* biash_ = (unsigned short*)(vthi_ + (size_t)NLK * DD); // 32 MB
    unsigned short* macc_  = biash_ + (size_t)NLQ * NLK;        // 16.8 MB
    float2* ml_  = (float2*)(macc_ + (size_t)NKC * NH * NLQ * HD);  // 1 MB
    short* aohi_ = (short*)(ml_ + (size_t)NKC * NH * NLQ);      // 2 MB
    short* aolo_ = aohi_ + (size_t)NLQ * DD;                    // 2 MB

    // 1) fused prep: QKV projection (576 blocks) + bias pack (4096 blocks)
    prep<<<dim3(NPROJ + 4096), 256, 0, stream>>>(Q, K, V, Win, bin, bias, mask,
                                                 qhi_, khi_, vthi_, biash_);

    // 2) attention (k-split NKC=8)
    attn_mfma<<<dim3(NH * 16 * NKC), 512, 0, stream>>>(qhi_, khi_, vthi_, biash_, macc_, ml_);

    // 3) combine partials -> ao (bf16 hi/lo)
    attn_combine<<<dim3(NH * NLQ / 4), 256, 0, stream>>>(macc_, ml_, aohi_, aolo_);

    // 4) out projection (W f32 staged)
    gemm_out<<<dim3(NLQ / 64, DD / 64), 256, 0, stream>>>(aohi_, aolo_, Wout, bout, out);
}

// Round 14
// 145.098 us; speedup vs baseline: 3.6047x; 1.0612x over previous
//
#include <hip/hip_runtime.h>
#include <math.h>

#define DD 512
#define NH 8
#define HD 64
#define NLQ 2048
#define NLK 8192
#define LOG2E 1.4426950408889634f
#define SCQ (0.125f * LOG2E)

typedef __attribute__((ext_vector_type(8))) short bf16x8;
typedef __attribute__((ext_vector_type(8))) unsigned short u16x8;
typedef __attribute__((ext_vector_type(4))) float f32x4;

#define MFMA16(a, b, c) __builtin_amdgcn_mfma_f32_16x16x32_bf16((a), (b), (c), 0, 0, 0)

__device__ __forceinline__ unsigned short f2bf(float x) {
    unsigned u = __builtin_bit_cast(unsigned, x);
    u += 0x7fffu + ((u >> 16) & 1u);
    return (unsigned short)(u >> 16);
}
__device__ __forceinline__ float bf2f(unsigned short h) {
    unsigned u = ((unsigned)h) << 16;
    return __builtin_bit_cast(float, u);
}
__device__ __forceinline__ unsigned short f2h(float x) {
    return __builtin_bit_cast(unsigned short, (_Float16)x);
}
__device__ __forceinline__ float h2f(unsigned short u) {
    return (float)__builtin_bit_cast(_Float16, u);
}
__device__ __forceinline__ int cvtpk(float a, float b) {
    int r;
    asm("v_cvt_pk_bf16_f32 %0, %1, %2" : "=v"(r) : "v"(a), "v"(b));
    return r;
}
__device__ __forceinline__ float max3f(float a, float b, float c) {
    return fmaxf(fmaxf(a, b), c);   // clang fuses to v_max3_f32
}
// bf2f of the low/high bf16 halves of a cvtpk-packed int
__device__ __forceinline__ float lobf(int w) {
    return __builtin_bit_cast(float, w << 16);
}
__device__ __forceinline__ float hibf(int w) {
    return __builtin_bit_cast(float, (int)(w & 0xffff0000));
}

// ---------------------------------------------------------------------------
// PREP (one launch, block-range fused):
//   blocks [0, 576):    QKV projection. bx=bid%144: <16 Q | <80 K | else V(tr).
//                       X f32 direct; W f32 -> hi/lo split IN STAGING.
//   blocks [576, 4672): bias+mask -> fp16 log2-units fragment pack.
// ---------------------------------------------------------------------------
#define NPROJ 576

__global__ __launch_bounds__(256) void prep(const float* __restrict__ Q,
                                            const float* __restrict__ K,
                                            const float* __restrict__ V,
                                            const float* __restrict__ Win,
                                            const float* __restrict__ bin,
                                            const float* __restrict__ bias,
                                            const int* __restrict__ mask,
                                            short* __restrict__ qhi,
                                            short* __restrict__ khi,
                                            short* __restrict__ vthi,
                                            unsigned short* __restrict__ bh)
{
    __shared__ __align__(16) short XsH[128 * 40];
    __shared__ __align__(16) short WsH[128 * 40];
    __shared__ __align__(16) short WsL[128 * 40];

    const int bid = blockIdx.x;
    if (bid >= NPROJ) {
        // ---- bias pack path (grid-fused; no LDS use) ----
        const int tid  = (bid - NPROJ) * 256 + threadIdx.x;
        const int tile = tid >> 6;          // (Qg*128 + kt)
        const int l    = tid & 63;
        const int q    = (tile >> 7) * 16 + (l & 15);
        const int kb   = (tile & 127) * 64 + 4 * (l >> 4);
        u16x8 o0v, o1v;
#pragma unroll
        for (int j = 0; j < 4; ++j) {
            const float4 bv = *(const float4*)&bias[(size_t)q * NLK + kb + 16 * j];
            const int4   mv = *(const int4*)&mask[kb + 16 * j];
            const float a[4] = {bv.x, bv.y, bv.z, bv.w};
            const int   m[4] = {mv.x, mv.y, mv.z, mv.w};
#pragma unroll
            for (int r = 0; r < 4; ++r) {
                const float v = (a[r] - 10000.f * (float)m[r]) * LOG2E;
                const int idx = j * 4 + r;
                if (idx < 8) o0v[idx] = f2h(v);
                else         o1v[idx - 8] = f2h(v);
            }
        }
        const size_t base = ((size_t)tid) * 16;
        *(u16x8*)&bh[base] = o0v;
        *(u16x8*)&bh[base + 8] = o1v;
        return;
    }

    // ---- QKV projection path ----
    const int o0 = (bid / 144) * 128;
    const int bx = bid % 144;
    const float* X; const float* Wf; const float* b; short* out;
    int r0; float scale; int tr;
    if (bx < 16)      { X = Q; r0 = bx * 128;        Wf = Win;               b = bin;          out = qhi;  scale = SCQ; tr = 0; }
    else if (bx < 80) { X = K; r0 = (bx - 16) * 128; Wf = Win + DD * DD;     b = bin + DD;     out = khi;  scale = 1.f; tr = 0; }
    else              { X = V; r0 = (bx - 80) * 128; Wf = Win + 2 * DD * DD; b = bin + 2 * DD; out = vthi; scale = 1.f; tr = 1; }

    const int t    = threadIdx.x;
    const int wid  = t >> 6;
    const int lane = t & 63;
    const int g  = lane >> 4;
    const int c  = lane & 15;
    const int wr = wid >> 1;
    const int wc = wid & 1;
    const int srow = t >> 1;
    const int sk   = (t & 1) * 16;

    float4 xf[4], wf[4];
    auto ld = [&](int kc) {
#pragma unroll
        for (int i = 0; i < 4; ++i) {
            xf[i] = *(const float4*)&X[(size_t)(r0 + srow) * DD + kc + sk + 4 * i];
            wf[i] = *(const float4*)&Wf[(size_t)(o0 + srow) * DD + kc + sk + 4 * i];
        }
    };
    auto st = [&]() {
#pragma unroll
        for (int i = 0; i < 2; ++i) {
            int4 xw;
            xw.x = cvtpk(xf[2 * i].x, xf[2 * i].y);
            xw.y = cvtpk(xf[2 * i].z, xf[2 * i].w);
            xw.z = cvtpk(xf[2 * i + 1].x, xf[2 * i + 1].y);
            xw.w = cvtpk(xf[2 * i + 1].z, xf[2 * i + 1].w);
            *(int4*)&XsH[srow * 40 + sk + 8 * i] = xw;
            const float4 a = wf[2 * i], bb = wf[2 * i + 1];
            int4 hw;
            hw.x = cvtpk(a.x, a.y);
            hw.y = cvtpk(a.z, a.w);
            hw.z = cvtpk(bb.x, bb.y);
            hw.w = cvtpk(bb.z, bb.w);
            int4 lw;
            lw.x = cvtpk(a.x - lobf(hw.x), a.y - hibf(hw.x));
            lw.y = cvtpk(a.z - lobf(hw.y), a.w - hibf(hw.y));
            lw.z = cvtpk(bb.x - lobf(hw.z), bb.y - hibf(hw.z));
            lw.w = cvtpk(bb.z - lobf(hw.w), bb.w - hibf(hw.w));
            *(int4*)&WsH[srow * 40 + sk + 8 * i] = hw;
            *(int4*)&WsL[srow * 40 + sk + 8 * i] = lw;
        }
    };

    f32x4 acc[4][4];
#pragma unroll
    for (int i = 0; i < 4; ++i)
#pragma unroll
        for (int j = 0; j < 4; ++j) acc[i][j] = (f32x4){0.f, 0.f, 0.f, 0.f};

    ld(0);
    for (int kc = 0; kc < DD; kc += 32) {
        __syncthreads();
        st();
        __syncthreads();
        if (kc + 32 < DD) ld(kc + 32);

        bf16x8 ah[4], bhf[4], blf[4];
#pragma unroll
        for (int qg = 0; qg < 4; ++qg)
            ah[qg] = *(const bf16x8*)&XsH[(64 * wr + 16 * qg + c) * 40 + 8 * g];
#pragma unroll
        for (int og = 0; og < 4; ++og) {
            const int adr = (64 * wc + 16 * og + c) * 40 + 8 * g;
            bhf[og] = *(const bf16x8*)&WsH[adr];
            blf[og] = *(const bf16x8*)&WsL[adr];
        }
#pragma unroll
        for (int qg = 0; qg < 4; ++qg)
#pragma unroll
            for (int og = 0; og < 4; ++og) {
                acc[qg][og] = MFMA16(ah[qg], bhf[og], acc[qg][og]);
                acc[qg][og] = MFMA16(ah[qg], blf[og], acc[qg][og]);
            }
    }

#pragma unroll
    for (int qg = 0; qg < 4; ++qg)
#pragma unroll
        for (int og = 0; og < 4; ++og) {
            const int col = o0 + 64 * wc + 16 * og + c;
            const float bo = b[col];
#pragma unroll
            for (int r = 0; r < 4; ++r) {
                const int row = r0 + 64 * wr + 16 * qg + 4 * g + r;
                const float v = (acc[qg][og][r] + bo) * scale;
                if (tr) out[(size_t)col * NLK + row] = (short)f2bf(v);
                else    out[(size_t)row * DD + col]  = (short)f2bf(v);
            }
        }
}

// ---------------------------------------------------------------------------
// Out-projection: 64x64 tiles (256 blocks), X hi/lo (from combine),
// W f32 -> hi/lo split in staging, 3-MFMA, f32 out.
// ---------------------------------------------------------------------------
__global__ __launch_bounds__(256) void gemm_out(const short* __restrict__ Xhi,
                                                const short* __restrict__ Xlo,
                                                const float* __restrict__ Wf,
                                                const float* __restrict__ b,
                                                float* __restrict__ Y)
{
    __shared__ __align__(16) short XsH[64 * 40];
    __shared__ __align__(16) short XsL[64 * 40];
    __shared__ __align__(16) short WsH[64 * 40];
    __shared__ __align__(16) short WsL[64 * 40];

    const int r0 = blockIdx.x * 64;
    const int o0 = blockIdx.y * 64;
    const int t    = threadIdx.x;
    const int wid  = t >> 6;
    const int lane = t & 63;
    const int g  = lane >> 4;
    const int c  = lane & 15;
    const int srow = t >> 2;
    const int sc8  = (t & 3) * 8;

    bf16x8 pxh, pxl;
    float4 wf0, wf1;
    auto ld = [&](int kc) {
        pxh = *(const bf16x8*)&Xhi[(size_t)(r0 + srow) * DD + kc + sc8];
        pxl = *(const bf16x8*)&Xlo[(size_t)(r0 + srow) * DD + kc + sc8];
        wf0 = *(const float4*)&Wf[(size_t)(o0 + srow) * DD + kc + sc8];
        wf1 = *(const float4*)&Wf[(size_t)(o0 + srow) * DD + kc + sc8 + 4];
    };
    auto st = [&]() {
        *(bf16x8*)&XsH[srow * 40 + sc8] = pxh;
        *(bf16x8*)&XsL[srow * 40 + sc8] = pxl;
        int4 hw;
        hw.x = cvtpk(wf0.x, wf0.y);
        hw.y = cvtpk(wf0.z, wf0.w);
        hw.z = cvtpk(wf1.x, wf1.y);
        hw.w = cvtpk(wf1.z, wf1.w);
        int4 lw;
        lw.x = cvtpk(wf0.x - lobf(hw.x), wf0.y - hibf(hw.x));
        lw.y = cvtpk(wf0.z - lobf(hw.y), wf0.w - hibf(hw.y));
        lw.z = cvtpk(wf1.x - lobf(hw.z), wf1.y - hibf(hw.z));
        lw.w = cvtpk(wf1.z - lobf(hw.w), wf1.w - hibf(hw.w));
        *(int4*)&WsH[srow * 40 + sc8] = hw;
        *(int4*)&WsL[srow * 40 + sc8] = lw;
    };

    f32x4 acc[4];
#pragma unroll
    for (int n = 0; n < 4; ++n) acc[n] = (f32x4){0.f, 0.f, 0.f, 0.f};

    ld(0);
    for (int kc = 0; kc < DD; kc += 32) {
        __syncthreads();
        st();
        __syncthreads();
        if (kc + 32 < DD) ld(kc + 32);

        bf16x8 ah, al, bh[4], bl[4];
        ah = *(const bf16x8*)&XsH[(wid * 16 + c) * 40 + 8 * g];
        al = *(const bf16x8*)&XsL[(wid * 16 + c) * 40 + 8 * g];
#pragma unroll
        for (int n = 0; n < 4; ++n) {
            const int adr = (16 * n + c) * 40 + 8 * g;
            bh[n] = *(const bf16x8*)&WsH[adr];
            bl[n] = *(const bf16x8*)&WsL[adr];
        }
#pragma unroll
        for (int n = 0; n < 4; ++n) {
            acc[n] = MFMA16(ah, bh[n], acc[n]);
            acc[n] = MFMA16(ah, bl[n], acc[n]);
            acc[n] = MFMA16(al, bh[n], acc[n]);
        }
    }

#pragma unroll
    for (int n = 0; n < 4; ++n) {
        const int col = o0 + 16 * n + c;
        const float bo = b[col];
#pragma unroll
        for (int r = 0; r < 4; ++r)
            Y[(size_t)(r0 + wid * 16 + 4 * g + r) * DD + col] = acc[n][r] + bo;
    }
}

// ---------------------------------------------------------------------------
// MFMA flash attention. R14: the P-redistribute (C/D-layout -> A-frag
// transpose) goes through a per-wave LDS scratch (psh, XOR-swizzled like ksh)
// instead of 16 ds_bpermute + 8 cndmask: 4 ds_write_b64 + 2 ds_read_b128,
// same-wave RAW (no barrier). Index algebra verified: store puts element k at
// (k&~3)^swz + (k&3); b128 read expects (k&~7)^swz + (k&7); equal since swz
// occupies bits 3-5. DS pipe was the ~87%-busy bottleneck (8 waves x 36 DS
// ops/tile). LDS 48KB -> 3 blocks/CU (DS-bound, so occupancy loss is cheap).
// (512,4): VGPR cap 128 -- (512,8) spilled (R9).
// ---------------------------------------------------------------------------
#define QT 128
#define KT 64
#define NKC 8
#define CHUNK (NLK / NKC)
#define NT (CHUNK / KT)

__global__ __launch_bounds__(512, 4) void attn_mfma(const short* __restrict__ qhi,
                                                    const short* __restrict__ khi,
                                                    const short* __restrict__ vthi,
                                                    const unsigned short* __restrict__ biash,
                                                    unsigned short* __restrict__ macc,
                                                    float2* __restrict__ mlb)
{
    __shared__ __align__(16) short ksh[2 * KT * HD];   // 16 KB
    __shared__ __align__(16) short vth[2 * KT * HD];   // 16 KB
    __shared__ __align__(16) short psh[8 * 16 * KT];   // 16 KB, per-wave 2 KB

    const int id = blockIdx.x;          // h*128 + qt*8 + kc
    const int h  = id >> 7;
    const int qt = (id >> 3) & 15;
    const int kc = id & 7;
    const int q0 = qt * QT;
    const int k0 = kc * CHUNK;

    const int t    = threadIdx.x;
    const int wid  = t >> 6;
    const int lane = t & 63;
    const int g  = lane >> 4;
    const int cl = lane & 15;
    const int swc = ((cl & 7) << 3);

    bf16x8 qah[2];
    {
        const size_t qr = (size_t)(q0 + wid * 16 + cl) * DD + h * HD;
        qah[0] = *(const bf16x8*)&qhi[qr + 8 * g];
        qah[1] = *(const bf16x8*)&qhi[qr + 32 + 8 * g];
    }

    const int v0 = (8 * g) ^ swc;
    const short* kbA0 = &ksh[cl * HD + v0];
    const short* kbB0 = &ksh[cl * HD + (v0 ^ 32)];
    const short* kbA1 = kbA0 + KT * HD;
    const short* kbB1 = kbB0 + KT * HD;
    const short* vbA0 = &vth[cl * HD + v0];
    const short* vbB0 = &vth[cl * HD + (v0 ^ 32)];
    const short* vbA1 = vbA0 + KT * HD;
    const short* vbB1 = vbB0 + KT * HD;

    const int kr0 = t >> 3;
    const int db0 = (t & 7) * 8;
    const int sw0 = ((kr0 & 7) << 3);
    short* wk0 = &ksh[kr0 * HD + (db0 ^ sw0)];
    short* wk1 = wk0 + KT * HD;
    short* wv0 = &vth[kr0 * HD + (db0 ^ sw0)];
    short* wv1 = wv0 + KT * HD;

    // per-wave P scratch: write 4x int2 (j=0..3), read 2x b128 (s=0..1).
    // element k lives at cl*64 + ((k&~3)^swc) + (k&3); reads use 8-aligned
    // bases so the same formula holds for (k&~7)^swc + (k&7).
    short* psw = &psh[wid * (16 * KT)];
    short* pw0 = &psw[cl * KT + (( 0 + 4 * g) ^ swc)];
    short* pw1 = &psw[cl * KT + ((16 + 4 * g) ^ swc)];
    short* pw2 = &psw[cl * KT + ((32 + 4 * g) ^ swc)];
    short* pw3 = &psw[cl * KT + ((48 + 4 * g) ^ swc)];
    const short* pr0 = &psw[cl * KT + ((8 * g) ^ swc)];
    const short* pr1 = &psw[cl * KT + ((32 + 8 * g) ^ swc)];

    const short* kgp = khi + (size_t)(k0 + kr0) * DD + h * HD + db0;
    const short* vgp = vthi + (size_t)(h * HD + kr0) * NLK + k0 + db0;
    const unsigned short* bgp =
        biash + (((size_t)(qt * 8 + wid) * 128 + kc * NT) << 10) + lane * 16;

    bf16x8 rkh, rvh;
    u16x8 bp0, bp1;
    rkh = *(const bf16x8*)kgp;  kgp += (size_t)KT * DD;
    rvh = *(const bf16x8*)vgp;  vgp += KT;
    bp0 = *(const u16x8*)bgp;
    bp1 = *(const u16x8*)(bgp + 8);  bgp += 1024;

    bf16x8 ones;
#pragma unroll
    for (int i = 0; i < 8; ++i) ones[i] = (short)0x3F80;

    f32x4 acco[4];
    f32x4 lacc = (f32x4){0.f, 0.f, 0.f, 0.f};
#pragma unroll
    for (int n = 0; n < 4; ++n) acco[n] = (f32x4){0.f, 0.f, 0.f, 0.f};
    float m_ = -1e30f;

    for (int it = 0; it < NT; ++it) {
        const int p = it & 1;
        const short* kA = p ? kbA1 : kbA0;
        const short* kB = p ? kbB1 : kbB0;
        const short* vA = p ? vbA1 : vbA0;
        const short* vB = p ? vbB1 : vbB0;
        short* wk = p ? wk1 : wk0;
        short* wv = p ? wv1 : wv0;

        *(bf16x8*)wk = rkh;
        *(bf16x8*)wv = rvh;
        __syncthreads();
        if (it + 1 < NT) {
            rkh = *(const bf16x8*)kgp;  kgp += (size_t)KT * DD;
            rvh = *(const bf16x8*)vgp;  vgp += KT;
        }

        // ---- C-in = bias fragment (mask + log2e prefolded) ----
        f32x4 sc[4];
#pragma unroll
        for (int j = 0; j < 4; ++j)
#pragma unroll
            for (int r = 0; r < 4; ++r) {
                const int i = j * 4 + r;
                sc[j][r] = h2f((i < 8) ? (unsigned short)bp0[i]
                                       : (unsigned short)bp1[i - 8]);
            }

        // ---- swapped QK^T accumulating onto bias ----
        __builtin_amdgcn_s_setprio(1);
#pragma unroll
        for (int j = 0; j < 4; ++j) {
            const bf16x8 kf0 = *(const bf16x8*)(kA + j * 16 * HD);
            const bf16x8 kf1 = *(const bf16x8*)(kB + j * 16 * HD);
            sc[j] = MFMA16(kf0, qah[0], sc[j]);
            sc[j] = MFMA16(kf1, qah[1], sc[j]);
        }
        __builtin_amdgcn_s_setprio(0);

        if (it + 1 < NT) {
            bp0 = *(const u16x8*)bgp;
            bp1 = *(const u16x8*)(bgp + 8);  bgp += 1024;
        }

        // ---- in-register softmax with defer-max (max3 trees) ----
        const float t0 = max3f(sc[0][0], sc[0][1], sc[0][2]);
        const float t1 = max3f(sc[0][3], sc[1][0], sc[1][1]);
        const float t2 = max3f(sc[1][2], sc[1][3], sc[2][0]);
        const float t3 = max3f(sc[2][1], sc[2][2], sc[2][3]);
        const float t4 = max3f(sc[3][0], sc[3][1], sc[3][2]);
        float tm = max3f(max3f(t0, t1, t2), max3f(t3, t4, sc[3][3]),
                         -1e30f);
        tm = fmaxf(tm, __shfl_xor(tm, 16));
        tm = fmaxf(tm, __shfl_xor(tm, 32));
        if (!__all(tm - m_ <= 11.5f)) {
            const float mn = fmaxf(m_, tm);
            const float al = exp2f(m_ - mn);
            float alr[4];
#pragma unroll
            for (int r = 0; r < 4; ++r) alr[r] = __shfl(al, 4 * g + r);
#pragma unroll
            for (int n = 0; n < 4; ++n)
#pragma unroll
                for (int r = 0; r < 4; ++r) acco[n][r] *= alr[r];
#pragma unroll
            for (int r = 0; r < 4; ++r) lacc[r] *= alr[r];
            m_ = mn;
        }
#pragma unroll
        for (int j = 0; j < 4; ++j)
#pragma unroll
            for (int r = 0; r < 4; ++r)
                sc[j][r] = exp2f(sc[j][r] - m_);

        // ---- pack P and redistribute via per-wave LDS (no barrier) ----
        *(int2*)pw0 = make_int2(cvtpk(sc[0][0], sc[0][1]), cvtpk(sc[0][2], sc[0][3]));
        *(int2*)pw1 = make_int2(cvtpk(sc[1][0], sc[1][1]), cvtpk(sc[1][2], sc[1][3]));
        *(int2*)pw2 = make_int2(cvtpk(sc[2][0], sc[2][1]), cvtpk(sc[2][2], sc[2][3]));
        *(int2*)pw3 = make_int2(cvtpk(sc[3][0], sc[3][1]), cvtpk(sc[3][2], sc[3][3]));
        bf16x8 pah[2];
        pah[0] = *(const bf16x8*)pr0;
        pah[1] = *(const bf16x8*)pr1;

        // ---- PV + l-sum (both on matrix pipe) ----
        __builtin_amdgcn_s_setprio(1);
#pragma unroll
        for (int n = 0; n < 4; ++n) {
            const bf16x8 vh0 = *(const bf16x8*)(vA + n * 16 * HD);
            const bf16x8 vh1 = *(const bf16x8*)(vB + n * 16 * HD);
            acco[n] = MFMA16(pah[0], vh0, acco[n]);
            acco[n] = MFMA16(pah[1], vh1, acco[n]);
        }
        lacc = MFMA16(pah[0], ones, lacc);
        lacc = MFMA16(pah[1], ones, lacc);
        __builtin_amdgcn_s_setprio(0);
    }

    // epilogue: normalize by 1/lacc[r] (same-lane, q = 4g+r aligned)
    f32x4 linv;
#pragma unroll
    for (int r = 0; r < 4; ++r) linv[r] = 1.f / lacc[r];
#pragma unroll
    for (int r = 0; r < 4; ++r) {
        const int q = q0 + wid * 16 + 4 * g + r;
        const size_t base = ((size_t)(kc * NH + h) * NLQ + q) * HD;
#pragma unroll
        for (int n = 0; n < 4; ++n)
            macc[base + 16 * n + cl] = f2h(acco[n][r] * linv[r]);
    }
    // route l[q=cl] to the g==0 store lane (m_ is already per q=cl)
    {
        const int srcl = ((cl >> 2) << 4) + cl;
        const float lc0 = __shfl(lacc[0], srcl);
        const float lc1 = __shfl(lacc[1], srcl);
        const float lc2 = __shfl(lacc[2], srcl);
        const float lc3 = __shfl(lacc[3], srcl);
        const int rr = cl & 3;
        const float lq = rr == 0 ? lc0 : rr == 1 ? lc1 : rr == 2 ? lc2 : lc3;
        if (g == 0)
            mlb[(size_t)(kc * NH + h) * NLQ + q0 + wid * 16 + cl] = make_float2(m_, lq);
    }
}

// ---------------------------------------------------------------------------
// Combine: partials pre-normalized; weight = exp2(m_c - M) * l_c.
// ---------------------------------------------------------------------------
__global__ __launch_bounds__(256) void attn_combine(const unsigned short* __restrict__ macc,
                                                    const float2* __restrict__ mlb,
                                                    short* __restrict__ aohi,
                                                    short* __restrict__ aolo)
{
    const int row = blockIdx.x * 4 + (threadIdx.x >> 6);  // h*NLQ + q
    const int d   = threadIdx.x & 63;
    float m[NKC], l[NKC];
#pragma unroll
    for (int c = 0; c < NKC; ++c) {
        const float2 v = mlb[(size_t)c * NH * NLQ + row];
        m[c] = v.x; l[c] = v.y;
    }
    float M = m[0];
#pragma unroll
    for (int c = 1; c < NKC; ++c) M = fmaxf(M, m[c]);
    float w[NKC], L = 0.f;
#pragma unroll
    for (int c = 0; c < NKC; ++c) { w[c] = exp2f(m[c] - M) * l[c]; L += w[c]; }
    float s = 0.f;
#pragma unroll
    for (int c = 0; c < NKC; ++c)
        s += h2f(macc[((size_t)c * NH * NLQ + row) * HD + d]) * w[c];
    const float v = s / L;
    const int hh = row >> 11;
    const int q  = row & (NLQ - 1);
    const size_t o = (size_t)q * DD + hh * HD + d;
    const unsigned short hb = f2bf(v);
    aohi[o] = (short)hb;
    aolo[o] = (short)f2bf(v - bf2f(hb));
}

extern "C" void kernel_launch(void* const* d_in, const int* in_sizes, int n_in,
                              void* d_out, int out_size, void* d_ws, size_t ws_size,
                              hipStream_t stream)
{
    (void)in_sizes; (void)n_in; (void)out_size; (void)ws_size;
    const float* Q    = (const float*)d_in[0];
    const float* K    = (const float*)d_in[1];
    const float* V    = (const float*)d_in[2];
    const int*   mask = (const int*)d_in[3];
    const float* bias = (const float*)d_in[4];
    const float* Win  = (const float*)d_in[5];
    const float* bin  = (const float*)d_in[6];
    const float* Wout = (const float*)d_in[7];
    const float* bout = (const float*)d_in[8];
    float* out = (float*)d_out;

    // ---- workspace (~72 MB flat) ----
    short* qhi_  = (short*)d_ws;                                // 2 MB
    short* khi_  = qhi_  + (size_t)NLQ * DD;                    // 8 MB
    short* vthi_ = khi_  + (size_t)NLK * DD;                    // 8 MB
    unsigned short* biash_ = (unsigned short*)(vthi_ + (size_t)NLK * DD); // 32 MB
    unsigned short* macc_  = biash_ + (size_t)NLQ * NLK;        // 16.8 MB
    float2* ml_  = (float2*)(macc_ + (size_t)NKC * NH * NLQ * HD);  // 1 MB
    short* aohi_ = (short*)(ml_ + (size_t)NKC * NH * NLQ);      // 2 MB
    short* aolo_ = aohi_ + (size_t)NLQ * DD;                    // 2 MB

    // 1) fused prep: QKV projection (576 blocks) + bias pack (4096 blocks)
    prep<<<dim3(NPROJ + 4096), 256, 0, stream>>>(Q, K, V, Win, bin, bias, mask,
                                                 qhi_, khi_, vthi_, biash_);

    // 2) attention (k-split NKC=8)
    attn_mfma<<<dim3(NH * 16 * NKC), 512, 0, stream>>>(qhi_, khi_, vthi_, biash_, macc_, ml_);

    // 3) combine partials -> ao (bf16 hi/lo)
    attn_combine<<<dim3(NH * NLQ / 4), 256, 0, stream>>>(macc_, ml_, aohi_, aolo_);

    // 4) out projection (W f32 staged)
    gemm_out<<<dim3(NLQ / 64, DD / 64), 256, 0, stream>>>(aohi_, aolo_, Wout, bout, out);
}